// Round 7
// baseline (10257.214 us; speedup 1.0000x reference)
//
#include <hip/hip_runtime.h>
#include <cstddef>

// Decoder: B=64, S=400, T=100, E=512, H=512
// R7 = R6 with the Ws-staging width bug fixed: R5/R6 staged W tiles with
// row=idx>>2,col16=(idx&3)<<4 but wrote only ONE u16x8 (8 shorts) per task,
// leaving half the LDS tile uninitialized -> NaN through MFMA. Correct
// decomposition: row=idx>>3, colg=(idx&7)<<3, one u16x8 per task,
// 6 iters for 192-row tiles (gi/gh W), 4 iters for 128-row (Wq).

#define Bdim 64
#define Sdim 400
#define Tdim 100
#define Edim 512
#define Hdim 512
#define H2   1024
#define H3   1536

typedef __attribute__((ext_vector_type(8))) short          bf16x8;
typedef __attribute__((ext_vector_type(8))) unsigned short u16x8;
typedef __attribute__((ext_vector_type(4))) float          f32x4;

__device__ __forceinline__ float bf2f(unsigned short u) {
    return __uint_as_float(((unsigned int)u) << 16);
}
__device__ __forceinline__ unsigned short f2bf(float f) {
    unsigned int x = __float_as_uint(f);
    x += 0x7fffu + ((x >> 16) & 1u);
    return (unsigned short)(x >> 16);
}
__device__ __forceinline__ float fast_tanh(float x) {
    float e = __expf(2.0f * x);
    return 1.0f - 2.0f / (e + 1.0f);
}
__device__ __forceinline__ float sigm(float x) {
    return 1.0f / (1.0f + __expf(-x));
}

// ---- OCP e4m3fn encode (one-time paths only) ----
__device__ __forceinline__ unsigned char f2fp8(float f) {
    unsigned u = __float_as_uint(f);
    unsigned s = (u >> 24) & 0x80u;
    float a = fabsf(f);
    if (a >= 448.0f) return (unsigned char)(s | 0x7Eu);
    if (a < 0.0009765625f) return (unsigned char)s;
    int e = (int)((u >> 23) & 0xFF) - 127;
    if (e < -6) {
        int q = (int)lrintf(a * 512.0f);
        return (unsigned char)(s | (unsigned)q);
    }
    unsigned mant = u & 0x7FFFFFu;
    unsigned keep = mant >> 20;
    unsigned rem  = mant & 0xFFFFFu;
    if (rem > 0x80000u || (rem == 0x80000u && (keep & 1u))) keep++;
    if (keep == 8u) { keep = 0u; e++; if (e > 8) return (unsigned char)(s | 0x7Eu); }
    return (unsigned char)(s | ((unsigned)(e + 7) << 3) | keep);
}

#if defined(__has_builtin)
#if __has_builtin(__builtin_amdgcn_cvt_pk_f32_fp8)
#define HWFP8 1
#endif
#endif
__device__ __forceinline__ float fp8sw(unsigned char v) {
    unsigned e = (v >> 3) & 15u, m = v & 7u, s = v >> 7;
    float f = e ? __uint_as_float(((e + 120u) << 23) | (m << 20))
                : (float)m * 0.001953125f;
    return s ? -f : f;
}
__device__ __forceinline__ void dec4(unsigned int w, float* o) {
#ifdef HWFP8
    auto lo = __builtin_amdgcn_cvt_pk_f32_fp8(w, false);
    auto hi = __builtin_amdgcn_cvt_pk_f32_fp8(w, true);
    o[0] = lo[0]; o[1] = lo[1]; o[2] = hi[0]; o[3] = hi[1];
#else
    o[0] = fp8sw(w & 0xFF); o[1] = fp8sw((w >> 8) & 0xFF);
    o[2] = fp8sw((w >> 16) & 0xFF); o[3] = fp8sw(w >> 24);
#endif
}

// ---------------- one-time kernels ----------------

__global__ void k_cvt(const float4* __restrict__ in, ushort4* __restrict__ out, int n4) {
    int i = blockIdx.x * blockDim.x + threadIdx.x;
    int stride = gridDim.x * blockDim.x;
    for (; i < n4; i += stride) {
        float4 v = in[i];
        ushort4 u;
        u.x = f2bf(v.x); u.y = f2bf(v.y); u.z = f2bf(v.z); u.w = f2bf(v.w);
        out[i] = u;
    }
}

__global__ void k_cvt8(const float4* __restrict__ in, uchar4* __restrict__ out, int n4) {
    int i = blockIdx.x * blockDim.x + threadIdx.x;
    int stride = gridDim.x * blockDim.x;
    for (; i < n4; i += stride) {
        float4 v = in[i];
        uchar4 u;
        u.x = f2fp8(v.x); u.y = f2fp8(v.y); u.z = f2fp8(v.z); u.w = f2fp8(v.w);
        out[i] = u;
    }
}

// all weight bf16 converts in one launch (segmented grid-stride)
__global__ void k_cvtW(
    const float4* __restrict__ Wk, const float4* __restrict__ Wih,
    const float4* __restrict__ Whh, const float4* __restrict__ Wp,
    const float4* __restrict__ Wq,
    ushort4* __restrict__ oWk, ushort4* __restrict__ oWih,
    ushort4* __restrict__ oWhh, ushort4* __restrict__ oWp,
    ushort4* __restrict__ oWq)
{
    int i = blockIdx.x * blockDim.x + threadIdx.x;
    int stride = gridDim.x * blockDim.x;
    for (; i < 1245184; i += stride) {
        const float4* src; ushort4* dst; int k = i;
        if (k < 131072)                     { src = Wk;  dst = oWk;  }
        else if ((k -= 131072) < 589824)    { src = Wih; dst = oWih; }
        else if ((k -= 589824) < 196608)    { src = Whh; dst = oWhh; }
        else if ((k -= 196608) < 262144)    { src = Wp;  dst = oWp;  }
        else { k -= 262144;                   src = Wq;  dst = oWq;  }
        float4 v = src[k];
        ushort4 u;
        u.x = f2bf(v.x); u.y = f2bf(v.y); u.z = f2bf(v.z); u.w = f2bf(v.w);
        dst[k] = u;
    }
}

__global__ __launch_bounds__(256) void k_init(
    const float* __restrict__ ef, const float* __restrict__ Wi,
    const float* __restrict__ bi, float* __restrict__ h0)
{
    __shared__ float efs[1024];
    int b = blockIdx.x, tid = threadIdx.x;
    for (int i = tid; i < 1024; i += 256) efs[i] = ef[(size_t)b * 1024 + i];
    __syncthreads();
    for (int j = tid; j < 512; j += 256) {
        const float4* w4 = (const float4*)(Wi + (size_t)j * 1024);
        float acc = 0.0f;
        for (int k4 = 0; k4 < 256; k4++) {
            float4 wv = w4[k4];
            int k = k4 << 2;
            acc = fmaf(efs[k],   wv.x, acc);
            acc = fmaf(efs[k+1], wv.y, acc);
            acc = fmaf(efs[k+2], wv.z, acc);
            acc = fmaf(efs[k+3], wv.w, acc);
        }
        h0[(size_t)b * 512 + j] = fast_tanh(acc + bi[j]);
    }
}

__global__ __launch_bounds__(512) void k_q0(
    const float* __restrict__ h, const float* __restrict__ Wq,
    float* __restrict__ qbuf)
{
    __shared__ float hs[512];
    int b = blockIdx.x, j = threadIdx.x;
    hs[j] = h[(size_t)b * 512 + j];
    __syncthreads();
    const float4* w4 = (const float4*)(Wq + (size_t)j * 512);
    float acc = 0.0f;
    #pragma unroll 4
    for (int k4 = 0; k4 < 128; k4++) {
        float4 wv = w4[k4];
        int k = k4 << 2;
        acc = fmaf(hs[k],   wv.x, acc);
        acc = fmaf(hs[k+1], wv.y, acc);
        acc = fmaf(hs[k+2], wv.z, acc);
        acc = fmaf(hs[k+3], wv.w, acc);
    }
    qbuf[(size_t)b * 512 + j] = acc;
}

// MFMA bf16 GEMM: C[M][N] = A[M][K] @ B[N][K]^T. (verified R2/R4)
__global__ __launch_bounds__(256) void k_mfma_gemm(
    const float* __restrict__ Af,
    const unsigned short* __restrict__ A0, const unsigned short* __restrict__ A1,
    const unsigned short* __restrict__ A2,
    int ld0, int ld1, int ld2, int s1, int s2,
    const unsigned short* __restrict__ Bw, int ldb,
    float* __restrict__ Cf, unsigned short* __restrict__ Cb,
    unsigned char* __restrict__ C8, int ldc,
    const float* __restrict__ bias, int K)
{
    __shared__ __attribute__((aligned(16))) unsigned short As[128][40];
    __shared__ __attribute__((aligned(16))) unsigned short Bs[128][40];
    int m0 = blockIdx.x << 7, n0 = blockIdx.y << 7;
    int tid = threadIdx.x;
    int wave = tid >> 6, lane = tid & 63;
    int wr = (wave >> 1) << 6, wc = (wave & 1) << 6;
    int fr = lane & 15, fq = lane >> 4;
    f32x4 acc[4][4];
    #pragma unroll
    for (int i = 0; i < 4; i++)
        #pragma unroll
        for (int j = 0; j < 4; j++)
            acc[i][j] = (f32x4){0.f, 0.f, 0.f, 0.f};
    int lrow = tid >> 1;
    int lk = (tid & 1) << 4;
    for (int k0 = 0; k0 < K; k0 += 32) {
        u16x8 av0, av1;
        if (Af) {
            const float* ap = Af + (size_t)(m0 + lrow) * ld0 + k0 + lk;
            float4 f0 = *(const float4*)ap;
            float4 f1 = *(const float4*)(ap + 4);
            float4 f2 = *(const float4*)(ap + 8);
            float4 f3 = *(const float4*)(ap + 12);
            av0[0]=f2bf(f0.x); av0[1]=f2bf(f0.y); av0[2]=f2bf(f0.z); av0[3]=f2bf(f0.w);
            av0[4]=f2bf(f1.x); av0[5]=f2bf(f1.y); av0[6]=f2bf(f1.z); av0[7]=f2bf(f1.w);
            av1[0]=f2bf(f2.x); av1[1]=f2bf(f2.y); av1[2]=f2bf(f2.z); av1[3]=f2bf(f2.w);
            av1[4]=f2bf(f3.x); av1[5]=f2bf(f3.y); av1[6]=f2bf(f3.z); av1[7]=f2bf(f3.w);
        } else {
            const unsigned short* Ap; int lda_, ka;
            if (k0 < s1)      { Ap = A0; lda_ = ld0; ka = k0; }
            else if (k0 < s2) { Ap = A1; lda_ = ld1; ka = k0 - s1; }
            else              { Ap = A2; lda_ = ld2; ka = k0 - s2; }
            const unsigned short* ap = Ap + (size_t)(m0 + lrow) * lda_ + ka + lk;
            av0 = *(const u16x8*)ap;
            av1 = *(const u16x8*)(ap + 8);
        }
        const unsigned short* bp_ = Bw + (size_t)(n0 + lrow) * ldb + k0 + lk;
        u16x8 bv0 = *(const u16x8*)bp_;
        u16x8 bv1 = *(const u16x8*)(bp_ + 8);
        __syncthreads();
        *(u16x8*)&As[lrow][lk] = av0;
        *(u16x8*)&As[lrow][lk + 8] = av1;
        *(u16x8*)&Bs[lrow][lk] = bv0;
        *(u16x8*)&Bs[lrow][lk + 8] = bv1;
        __syncthreads();
        bf16x8 af[4], bf[4];
        #pragma unroll
        for (int i = 0; i < 4; i++) {
            af[i] = *(const bf16x8*)&As[wr + (i << 4) + fr][fq << 3];
            bf[i] = *(const bf16x8*)&Bs[wc + (i << 4) + fr][fq << 3];
        }
        #pragma unroll
        for (int i = 0; i < 4; i++)
            #pragma unroll
            for (int j = 0; j < 4; j++)
                acc[i][j] = __builtin_amdgcn_mfma_f32_16x16x32_bf16(af[i], bf[j], acc[i][j], 0, 0, 0);
    }
    #pragma unroll
    for (int j = 0; j < 4; j++) {
        int col = n0 + wc + (j << 4) + fr;
        float bv = bias ? bias[col] : 0.0f;
        #pragma unroll
        for (int i = 0; i < 4; i++) {
            int rbase = m0 + wr + (i << 4) + (fq << 2);
            #pragma unroll
            for (int r = 0; r < 4; r++) {
                float v = acc[i][j][r] + bv;
                if (C8)      C8[(size_t)(rbase + r) * ldc + col] = f2fp8(v);
                else if (Cb) Cb[(size_t)(rbase + r) * ldc + col] = f2bf(v);
                else         Cf[(size_t)(rbase + r) * ldc + col] = v;
            }
        }
    }
}

// ---------------- per-step kernel 1: attention ----------------
__global__ __launch_bounds__(256) void k_attn2(
    const unsigned char* __restrict__ pkb8, const unsigned char* __restrict__ ehb8,
    const float* __restrict__ qbuf, const float* __restrict__ qpart,
    const float* __restrict__ We,
    float* __restrict__ ctxp, float* __restrict__ mcb, float* __restrict__ sumc,
    int t)
{
    int bid = blockIdx.x;
    int b = bid >> 3, c = bid & 7;
    int s0 = c * 50;
    int tid = threadIdx.x, wave = tid >> 6, lane = tid & 63;
    __shared__ float qS[512];
    __shared__ float eL[52], pL[52];

    if (t == 0) {
        for (int j = tid; j < 512; j += 256) qS[j] = qbuf[(size_t)b * 512 + j];
    } else {
        for (int j = tid; j < 512; j += 256) {
            float s = 0.0f;
            #pragma unroll
            for (int cc = 0; cc < 8; cc++)
                s += qpart[(((size_t)(cc * 64 + b)) << 9) + j];
            qS[j] = s;
        }
    }
    __syncthreads();

    float q8[8], w8[8];
    {
        #pragma unroll
        for (int jj = 0; jj < 8; jj++) q8[jj] = qS[(lane << 3) + jj];
        const float4* wp = (const float4*)(We + (lane << 3));
        float4 w0 = wp[0], w1 = wp[1];
        w8[0]=w0.x; w8[1]=w0.y; w8[2]=w0.z; w8[3]=w0.w;
        w8[4]=w1.x; w8[5]=w1.y; w8[6]=w1.z; w8[7]=w1.w;
    }
    // energies, one wave per s row
    for (int sl = wave; sl < 50; sl += 4) {
        const unsigned char* pr = pkb8 + ((size_t)(b * Sdim + s0 + sl) << 9) + (lane << 3);
        uint2 u = *(const uint2*)pr;
        float p[8];
        dec4(u.x, p); dec4(u.y, p + 4);
        float sum = 0.0f;
        #pragma unroll
        for (int jj = 0; jj < 8; jj++)
            sum = fmaf(fast_tanh(q8[jj] + p[jj]), w8[jj], sum);
        #pragma unroll
        for (int off = 32; off > 0; off >>= 1) sum += __shfl_xor(sum, off, 64);
        if (lane == 0) eL[sl] = sum;
    }
    __syncthreads();
    // chunk-local softmax stats with max subtraction
    if (wave == 0) {
        float ev = (lane < 50) ? eL[lane] : -3.0e38f;
        float mx = ev;
        #pragma unroll
        for (int off = 32; off > 0; off >>= 1) mx = fmaxf(mx, __shfl_xor(mx, off, 64));
        float pv = (lane < 50) ? __expf(ev - mx) : 0.0f;
        if (lane < 50) pL[lane] = pv;
        float s = pv;
        #pragma unroll
        for (int off = 32; off > 0; off >>= 1) s += __shfl_xor(s, off, 64);
        if (lane == 0) { mcb[b * 8 + c] = mx; sumc[b * 8 + c] = s; }
    }
    __syncthreads();
    // unnormalized context partial; thread owns 4 dims
    int d0 = tid << 2;
    float a0 = 0.f, a1 = 0.f, a2 = 0.f, a3 = 0.f;
    const unsigned char* eb = ehb8 + ((size_t)(b * Sdim + s0) << 10) + d0;
    for (int sl = 0; sl < 50; sl++) {
        float pp = pL[sl];
        unsigned int u = *(const unsigned int*)(eb + ((size_t)sl << 10));
        float v[4];
        dec4(u, v);
        a0 = fmaf(pp, v[0], a0);
        a1 = fmaf(pp, v[1], a1);
        a2 = fmaf(pp, v[2], a2);
        a3 = fmaf(pp, v[3], a3);
    }
    *(float4*)&ctxp[(((size_t)(b * 8 + c)) << 10) + d0] = make_float4(a0, a1, a2, a3);
}

// ---------------- per-step kernel 2: GRU + gates + q-partials ----------------
// 8 blocks x 256 thr (4 waves). Block c owns j-slice j0=64c coupled across the
// 3 gates: full-K MFMA -> gates in registers -> h(t) -> qpart[c].
__global__ __launch_bounds__(256) void k_gru(
    const float* __restrict__ ctxp, const float* __restrict__ mcb,
    const float* __restrict__ sumc,
    const float* __restrict__ hb_old, float* __restrict__ hb_new,
    const unsigned short* __restrict__ Wihb, const unsigned short* __restrict__ Whhb,
    const unsigned short* __restrict__ Wqb, const unsigned short* __restrict__ giEb,
    const float* __restrict__ bih, const float* __restrict__ bhh,
    float* __restrict__ qpart, unsigned short* __restrict__ csb,
    unsigned short* __restrict__ dsb, float* __restrict__ ds,
    float* __restrict__ hlast, int t, int last)
{
    __shared__ __attribute__((aligned(16))) unsigned short As[64][72];   // A tiles / h_new
    __shared__ __attribute__((aligned(16))) unsigned short Ws[192][72];  // W rows / WqS
    __shared__ float sc8[64][8];   // online-softmax combine weights e^{m_c-M}/tot
    int c = blockIdx.x, j0 = c << 6;
    int tid = threadIdx.x, wave = tid >> 6, lane = tid & 63;
    int fr = lane & 15, fq = lane >> 4;

    if (tid < 64) {
        int b = tid;
        const float* mc = mcb + b * 8;
        const float* lc = sumc + b * 8;
        float M = mc[0];
        #pragma unroll
        for (int cc = 1; cc < 8; cc++) M = fmaxf(M, mc[cc]);
        float ee[8], tot = 0.0f;
        #pragma unroll
        for (int cc = 0; cc < 8; cc++) { ee[cc] = __expf(mc[cc] - M); tot += ee[cc] * lc[cc]; }
        float inv = 1.0f / tot;
        #pragma unroll
        for (int cc = 0; cc < 8; cc++) sc8[b][cc] = ee[cc] * inv;
    }

    f32x4 gacc[3][4], hacc[3][4];
    #pragma unroll
    for (int g = 0; g < 3; g++)
        #pragma unroll
        for (int i = 0; i < 4; i++) {
            gacc[g][i] = (f32x4){0.f,0.f,0.f,0.f};
            hacc[g][i] = (f32x4){0.f,0.f,0.f,0.f};
        }

    int sr = tid >> 2, scg = (tid & 3) << 4;       // As staging: row, 16-col group

    // ---- gi: ctx part, K=1024 (16 chunks of 64) ----
    for (int kc = 0; kc < 16; kc++) {
        __syncthreads();
        // stage As: weighted-combine 8 ctx partials (b-major layout), bf16
        {
            float4 a0 = {0,0,0,0}, a1 = {0,0,0,0}, a2 = {0,0,0,0}, a3 = {0,0,0,0};
            #pragma unroll
            for (int cc = 0; cc < 8; cc++) {
                float sc = sc8[sr][cc];
                const float* p = ctxp + (((size_t)(sr * 8 + cc)) << 10) + (kc << 6) + scg;
                float4 v0 = *(const float4*)p;
                float4 v1 = *(const float4*)(p + 4);
                float4 v2 = *(const float4*)(p + 8);
                float4 v3 = *(const float4*)(p + 12);
                a0.x = fmaf(sc, v0.x, a0.x); a0.y = fmaf(sc, v0.y, a0.y);
                a0.z = fmaf(sc, v0.z, a0.z); a0.w = fmaf(sc, v0.w, a0.w);
                a1.x = fmaf(sc, v1.x, a1.x); a1.y = fmaf(sc, v1.y, a1.y);
                a1.z = fmaf(sc, v1.z, a1.z); a1.w = fmaf(sc, v1.w, a1.w);
                a2.x = fmaf(sc, v2.x, a2.x); a2.y = fmaf(sc, v2.y, a2.y);
                a2.z = fmaf(sc, v2.z, a2.z); a2.w = fmaf(sc, v2.w, a2.w);
                a3.x = fmaf(sc, v3.x, a3.x); a3.y = fmaf(sc, v3.y, a3.y);
                a3.z = fmaf(sc, v3.z, a3.z); a3.w = fmaf(sc, v3.w, a3.w);
            }
            u16x8 u0, u1;
            u0[0]=f2bf(a0.x); u0[1]=f2bf(a0.y); u0[2]=f2bf(a0.z); u0[3]=f2bf(a0.w);
            u0[4]=f2bf(a1.x); u0[5]=f2bf(a1.y); u0[6]=f2bf(a1.z); u0[7]=f2bf(a1.w);
            u1[0]=f2bf(a2.x); u1[1]=f2bf(a2.y); u1[2]=f2bf(a2.z); u1[3]=f2bf(a2.w);
            u1[4]=f2bf(a3.x); u1[5]=f2bf(a3.y); u1[6]=f2bf(a3.z); u1[7]=f2bf(a3.w);
            *(u16x8*)&As[sr][scg]     = u0;
            *(u16x8*)&As[sr][scg + 8] = u1;
            if ((kc >> 1) == c) {   // persist combined ctx (this block's k-range)
                unsigned short* cp = csb + (((size_t)(sr * Tdim + t)) << 10) + (kc << 6) + scg;
                *(u16x8*)cp = u0;
                *(u16x8*)(cp + 8) = u1;
            }
        }
        // stage Ws: 192 gate-rows x 64 k  (1536 u16x8 tasks = 6 x 256)
        #pragma unroll
        for (int it = 0; it < 6; it++) {
            int idx = tid + (it << 8);
            int row = idx >> 3, colg = (idx & 7) << 3;
            int g = row >> 6, jj = row & 63;
            *(u16x8*)&Ws[row][colg] =
                *(const u16x8*)(Wihb + ((size_t)(g * 512 + j0 + jj)) * H3 + 512 + (kc << 6) + colg);
        }
        __syncthreads();
        #pragma unroll
        for (int s = 0; s < 2; s++) {
            bf16x8 af[4];
            #pragma unroll
            for (int i = 0; i < 4; i++)
                af[i] = *(const bf16x8*)&As[(i << 4) + fr][(s << 5) + (fq << 3)];
            #pragma unroll
            for (int g = 0; g < 3; g++) {
                bf16x8 bf = *(const bf16x8*)&Ws[(g << 6) + (wave << 4) + fr][(s << 5) + (fq << 3)];
                #pragma unroll
                for (int i = 0; i < 4; i++)
                    gacc[g][i] = __builtin_amdgcn_mfma_f32_16x16x32_bf16(af[i], bf, gacc[g][i], 0, 0, 0);
            }
        }
    }

    // ---- gh: K=512 (8 chunks of 64) ----
    for (int kc = 0; kc < 8; kc++) {
        __syncthreads();
        {
            const float* p = hb_old + (size_t)sr * 512 + (kc << 6) + scg;
            float4 v0 = *(const float4*)p;
            float4 v1 = *(const float4*)(p + 4);
            float4 v2 = *(const float4*)(p + 8);
            float4 v3 = *(const float4*)(p + 12);
            u16x8 u0, u1;
            u0[0]=f2bf(v0.x); u0[1]=f2bf(v0.y); u0[2]=f2bf(v0.z); u0[3]=f2bf(v0.w);
            u0[4]=f2bf(v1.x); u0[5]=f2bf(v1.y); u0[6]=f2bf(v1.z); u0[7]=f2bf(v1.w);
            u1[0]=f2bf(v2.x); u1[1]=f2bf(v2.y); u1[2]=f2bf(v2.z); u1[3]=f2bf(v2.w);
            u1[4]=f2bf(v3.x); u1[5]=f2bf(v3.y); u1[6]=f2bf(v3.z); u1[7]=f2bf(v3.w);
            *(u16x8*)&As[sr][scg]     = u0;
            *(u16x8*)&As[sr][scg + 8] = u1;
        }
        #pragma unroll
        for (int it = 0; it < 6; it++) {
            int idx = tid + (it << 8);
            int row = idx >> 3, colg = (idx & 7) << 3;
            int g = row >> 6, jj = row & 63;
            *(u16x8*)&Ws[row][colg] =
                *(const u16x8*)(Whhb + ((size_t)(g * 512 + j0 + jj)) * Hdim + (kc << 6) + colg);
        }
        __syncthreads();
        #pragma unroll
        for (int s = 0; s < 2; s++) {
            bf16x8 af[4];
            #pragma unroll
            for (int i = 0; i < 4; i++)
                af[i] = *(const bf16x8*)&As[(i << 4) + fr][(s << 5) + (fq << 3)];
            #pragma unroll
            for (int g = 0; g < 3; g++) {
                bf16x8 bf = *(const bf16x8*)&Ws[(g << 6) + (wave << 4) + fr][(s << 5) + (fq << 3)];
                #pragma unroll
                for (int i = 0; i < 4; i++)
                    hacc[g][i] = __builtin_amdgcn_mfma_f32_16x16x32_bf16(af[i], bf, hacc[g][i], 0, 0, 0);
            }
        }
    }

    // ---- gates in registers; write h(t); stage h_new slice into As ----
    __syncthreads();   // all waves done reading As/Ws
    {
        int j = j0 + (wave << 4) + fr;
        float bi0 = bih[j], bi1 = bih[512 + j], bi2 = bih[1024 + j];
        float bh0 = bhh[j], bh1 = bhh[512 + j], bh2 = bhh[1024 + j];
        #pragma unroll
        for (int i = 0; i < 4; i++) {
            #pragma unroll
            for (int r4 = 0; r4 < 4; r4++) {
                int b = (i << 4) + (fq << 2) + r4;
                size_t m = (size_t)b * Tdim + t;
                const unsigned short* ge = giEb + m * H3;
                float gi0 = gacc[0][i][r4] + bf2f(ge[j])        + bi0;
                float gi1 = gacc[1][i][r4] + bf2f(ge[512 + j])  + bi1;
                float gi2 = gacc[2][i][r4] + bf2f(ge[1024 + j]) + bi2;
                float gh0 = hacc[0][i][r4] + bh0;
                float gh1 = hacc[1][i][r4] + bh1;
                float gh2 = hacc[2][i][r4] + bh2;
                float rg = sigm(gi0 + gh0);
                float zz = sigm(gi1 + gh1);
                float nn = fast_tanh(gi2 + rg * gh2);
                float hold = hb_old[(size_t)b * 512 + j];
                float hn = (1.0f - zz) * nn + zz * hold;
                hb_new[(size_t)b * 512 + j] = hn;
                ds[m * 512 + j] = hn;
                dsb[m * 512 + j] = f2bf(hn);
                if (last) hlast[(size_t)b * 512 + j] = hn;
                As[b][(wave << 4) + fr] = f2bf(hn);   // hS[b][j-j0]
            }
        }
    }

    // ---- qpart[c] = h_new[:, slice] @ Wq[:, slice]^T  (M=64,N=512,K=64) ----
    for (int ch = 0; ch < 4; ch++) {
        __syncthreads();
        #pragma unroll
        for (int it = 0; it < 4; it++) {   // stage WqS: 128 rows x 64 k = 1024 u16x8
            int idx = tid + (it << 8);
            int row = idx >> 3, colg = (idx & 7) << 3;
            *(u16x8*)&Ws[row][colg] =
                *(const u16x8*)(Wqb + ((size_t)(ch * 128 + row)) * 512 + j0 + colg);
        }
        __syncthreads();
        f32x4 qa[2][4];
        #pragma unroll
        for (int u = 0; u < 2; u++)
            #pragma unroll
            for (int i = 0; i < 4; i++)
                qa[u][i] = (f32x4){0.f,0.f,0.f,0.f};
        #pragma unroll
        for (int s = 0; s < 2; s++) {
            bf16x8 af[4];
            #pragma unroll
            for (int i = 0; i < 4; i++)
                af[i] = *(const bf16x8*)&As[(i << 4) + fr][(s << 5) + (fq << 3)];
            #pragma unroll
            for (int u = 0; u < 2; u++) {
                bf16x8 bf = *(const bf16x8*)&Ws[(((wave << 1) + u) << 4) + fr][(s << 5) + (fq << 3)];
                #pragma unroll
                for (int i = 0; i < 4; i++)
                    qa[u][i] = __builtin_amdgcn_mfma_f32_16x16x32_bf16(af[i], bf, qa[u][i], 0, 0, 0);
            }
        }
        #pragma unroll
        for (int u = 0; u < 2; u++) {
            int jq = (ch << 7) + (((wave << 1) + u) << 4) + fr;
            #pragma unroll
            for (int i = 0; i < 4; i++) {
                #pragma unroll
                for (int r4 = 0; r4 < 4; r4++) {
                    int b = (i << 4) + (fq << 2) + r4;
                    qpart[(((size_t)(c * 64 + b)) << 9) + jq] = qa[u][i][r4];
                }
            }
        }
    }
}

extern "C" void kernel_launch(void* const* d_in, const int* in_sizes, int n_in,
                              void* d_out, int out_size, void* d_ws, size_t ws_size,
                              hipStream_t stream) {
    const float* te  = (const float*)d_in[0];
    const float* eh  = (const float*)d_in[1];
    const float* ef  = (const float*)d_in[2];
    const float* Wi  = (const float*)d_in[3];
    const float* bi  = (const float*)d_in[4];
    const float* Wk  = (const float*)d_in[5];
    const float* Wq  = (const float*)d_in[6];
    const float* We  = (const float*)d_in[7];
    const float* Wih = (const float*)d_in[8];
    const float* Whh = (const float*)d_in[9];
    const float* bih = (const float*)d_in[10];
    const float* bhh = (const float*)d_in[11];
    const float* Wp  = (const float*)d_in[12];
    const float* bp  = (const float*)d_in[13];

    float* out     = (float*)d_out;
    float* out_ds  = out;
    float* out_hl  = out + (size_t)Bdim * Tdim * Hdim;
    float* out_pre = out_hl + (size_t)Bdim * Hdim;

    // ---- workspace ----
    char* w = (char*)d_ws;
    size_t o = 0;
    unsigned char*  pkb8 = (unsigned char*)(w + o);  o += (size_t)25600 * 512;
    unsigned char*  ehb8 = (unsigned char*)(w + o);  o += (size_t)25600 * 1024;
    unsigned short* teb  = (unsigned short*)(w + o); o += (size_t)6400 * 512 * 2;
    unsigned short* Wkb  = (unsigned short*)(w + o); o += (size_t)512 * 1024 * 2;
    unsigned short* Wihb = (unsigned short*)(w + o); o += (size_t)1536 * 1536 * 2;
    unsigned short* Whhb = (unsigned short*)(w + o); o += (size_t)1536 * 512 * 2;
    unsigned short* Wpb  = (unsigned short*)(w + o); o += (size_t)512 * 2048 * 2;
    unsigned short* Wqb  = (unsigned short*)(w + o); o += (size_t)512 * 512 * 2;
    unsigned short* dsb  = (unsigned short*)(w + o); o += (size_t)6400 * 512 * 2;
    unsigned short* csb  = (unsigned short*)(w + o); o += (size_t)6400 * 1024 * 2;
    unsigned short* giEb = (unsigned short*)(w + o); o += (size_t)6400 * 1536 * 2;
    float* qbuf  = (float*)(w + o); o += (size_t)Bdim * 512 * 4;
    float* hbuf  = (float*)(w + o); o += (size_t)2 * Bdim * 512 * 4;   // ping-pong
    float* ctxp  = (float*)(w + o); o += (size_t)Bdim * 8 * 1024 * 4;
    float* mcb   = (float*)(w + o); o += 512 * 4;
    float* sumc  = (float*)(w + o); o += 512 * 4;
    float* qpart = (float*)(w + o); o += (size_t)8 * Bdim * 512 * 4;

    // ---- one-time prep (7 dispatches) ----
    k_cvt8<<<2048, 256, 0, stream>>>((const float4*)eh, (uchar4*)ehb8, 6553600);
    k_cvt<<<512, 256, 0, stream>>>((const float4*)te, (ushort4*)teb, 819200);
    k_cvtW<<<1024, 256, 0, stream>>>(
        (const float4*)Wk, (const float4*)Wih, (const float4*)Whh,
        (const float4*)Wp, (const float4*)Wq,
        (ushort4*)Wkb, (ushort4*)Wihb, (ushort4*)Whhb, (ushort4*)Wpb, (ushort4*)Wqb);
    k_init<<<Bdim, 256, 0, stream>>>(ef, Wi, bi, hbuf);
    k_q0<<<Bdim, 512, 0, stream>>>(hbuf, Wq, qbuf);
    // proj_key = eh(f32) @ Wkb^T -> pkb8 (fp8), M=25600 N=512 K=1024
    k_mfma_gemm<<<dim3(200, 4), 256, 0, stream>>>(
        eh, nullptr, nullptr, nullptr, 1024, 0, 0, 1024, 1024,
        Wkb, 1024, nullptr, nullptr, pkb8, 512, nullptr, 1024);
    // gi_embed = teb @ Wihb[:, :512]^T -> giEb (bf16), M=6400 N=1536 K=512
    k_mfma_gemm<<<dim3(50, 12), 256, 0, stream>>>(
        nullptr, teb, teb, teb, 512, 512, 512, 512, 512,
        Wihb, 1536, nullptr, giEb, nullptr, 1536, nullptr, 512);

    // ---- scan: 2 dispatches per step ----
    for (int t = 0; t < Tdim; t++) {
        float* hb_old = hbuf + (size_t)(t & 1) * 32768;
        float* hb_new = hbuf + (size_t)((t + 1) & 1) * 32768;
        k_attn2<<<512, 256, 0, stream>>>(pkb8, ehb8, qbuf, qpart, We, ctxp, mcb, sumc, t);
        k_gru<<<8, 256, 0, stream>>>(ctxp, mcb, sumc, hb_old, hb_new,
                                     Wihb, Whhb, Wqb, giEb, bih, bhh,
                                     qpart, csb, dsb, out_ds, out_hl,
                                     t, (t == Tdim - 1) ? 1 : 0);
    }

    // ---- final: pre = [teb | dsb | csb] @ Wpb^T + bp, M=6400 N=512 K=2048 ----
    k_mfma_gemm<<<dim3(50, 4), 256, 0, stream>>>(
        nullptr, teb, dsb, csb, 512, 512, 1024, 512, 1024,
        Wpb, 2048, out_pre, nullptr, nullptr, 512, bp, 2048);
}

// Round 8
// 9517.179 us; speedup vs baseline: 1.0778x; 1.0778x over previous
//
#include <hip/hip_runtime.h>
#include <cstddef>

// Decoder: B=64, S=400, T=100, E=512, H=512
// R8: 2 WIDE dispatches/step (R7's k_gru at 8 blocks was the regression:
// ~60-70us on 8 CUs). Now:
//  k_attn3: 64 blocks (1/batch), full-400 softmax in-block, writes combined
//           normalized bf16 ctx straight to csb[b][t] (no partial buffers).
//  k_gru2:  32 blocks (4 M-groups x 8 j-slices), M=16 full-K MFMA GRU,
//           gate-coupled in-wave, gates in regs, h(t), K-sliced q-partials.

#define Bdim 64
#define Sdim 400
#define Tdim 100
#define Edim 512
#define Hdim 512
#define H2   1024
#define H3   1536

typedef __attribute__((ext_vector_type(8))) short          bf16x8;
typedef __attribute__((ext_vector_type(8))) unsigned short u16x8;
typedef __attribute__((ext_vector_type(4))) float          f32x4;

__device__ __forceinline__ float bf2f(unsigned short u) {
    return __uint_as_float(((unsigned int)u) << 16);
}
__device__ __forceinline__ unsigned short f2bf(float f) {
    unsigned int x = __float_as_uint(f);
    x += 0x7fffu + ((x >> 16) & 1u);
    return (unsigned short)(x >> 16);
}
__device__ __forceinline__ float fast_tanh(float x) {
    float e = __expf(2.0f * x);
    return 1.0f - 2.0f / (e + 1.0f);
}
__device__ __forceinline__ float sigm(float x) {
    return 1.0f / (1.0f + __expf(-x));
}

// ---- OCP e4m3fn encode (one-time paths only) ----
__device__ __forceinline__ unsigned char f2fp8(float f) {
    unsigned u = __float_as_uint(f);
    unsigned s = (u >> 24) & 0x80u;
    float a = fabsf(f);
    if (a >= 448.0f) return (unsigned char)(s | 0x7Eu);
    if (a < 0.0009765625f) return (unsigned char)s;
    int e = (int)((u >> 23) & 0xFF) - 127;
    if (e < -6) {
        int q = (int)lrintf(a * 512.0f);
        return (unsigned char)(s | (unsigned)q);
    }
    unsigned mant = u & 0x7FFFFFu;
    unsigned keep = mant >> 20;
    unsigned rem  = mant & 0xFFFFFu;
    if (rem > 0x80000u || (rem == 0x80000u && (keep & 1u))) keep++;
    if (keep == 8u) { keep = 0u; e++; if (e > 8) return (unsigned char)(s | 0x7Eu); }
    return (unsigned char)(s | ((unsigned)(e + 7) << 3) | keep);
}

#if defined(__has_builtin)
#if __has_builtin(__builtin_amdgcn_cvt_pk_f32_fp8)
#define HWFP8 1
#endif
#endif
__device__ __forceinline__ float fp8sw(unsigned char v) {
    unsigned e = (v >> 3) & 15u, m = v & 7u, s = v >> 7;
    float f = e ? __uint_as_float(((e + 120u) << 23) | (m << 20))
                : (float)m * 0.001953125f;
    return s ? -f : f;
}
__device__ __forceinline__ void dec4(unsigned int w, float* o) {
#ifdef HWFP8
    auto lo = __builtin_amdgcn_cvt_pk_f32_fp8(w, false);
    auto hi = __builtin_amdgcn_cvt_pk_f32_fp8(w, true);
    o[0] = lo[0]; o[1] = lo[1]; o[2] = hi[0]; o[3] = hi[1];
#else
    o[0] = fp8sw(w & 0xFF); o[1] = fp8sw((w >> 8) & 0xFF);
    o[2] = fp8sw((w >> 16) & 0xFF); o[3] = fp8sw(w >> 24);
#endif
}

// ---------------- one-time kernels ----------------

__global__ void k_cvt(const float4* __restrict__ in, ushort4* __restrict__ out, int n4) {
    int i = blockIdx.x * blockDim.x + threadIdx.x;
    int stride = gridDim.x * blockDim.x;
    for (; i < n4; i += stride) {
        float4 v = in[i];
        ushort4 u;
        u.x = f2bf(v.x); u.y = f2bf(v.y); u.z = f2bf(v.z); u.w = f2bf(v.w);
        out[i] = u;
    }
}

__global__ void k_cvt8(const float4* __restrict__ in, uchar4* __restrict__ out, int n4) {
    int i = blockIdx.x * blockDim.x + threadIdx.x;
    int stride = gridDim.x * blockDim.x;
    for (; i < n4; i += stride) {
        float4 v = in[i];
        uchar4 u;
        u.x = f2fp8(v.x); u.y = f2fp8(v.y); u.z = f2fp8(v.z); u.w = f2fp8(v.w);
        out[i] = u;
    }
}

// all weight bf16 converts in one launch (segmented grid-stride)
__global__ void k_cvtW(
    const float4* __restrict__ Wk, const float4* __restrict__ Wih,
    const float4* __restrict__ Whh, const float4* __restrict__ Wp,
    const float4* __restrict__ Wq,
    ushort4* __restrict__ oWk, ushort4* __restrict__ oWih,
    ushort4* __restrict__ oWhh, ushort4* __restrict__ oWp,
    ushort4* __restrict__ oWq)
{
    int i = blockIdx.x * blockDim.x + threadIdx.x;
    int stride = gridDim.x * blockDim.x;
    for (; i < 1245184; i += stride) {
        const float4* src; ushort4* dst; int k = i;
        if (k < 131072)                     { src = Wk;  dst = oWk;  }
        else if ((k -= 131072) < 589824)    { src = Wih; dst = oWih; }
        else if ((k -= 589824) < 196608)    { src = Whh; dst = oWhh; }
        else if ((k -= 196608) < 262144)    { src = Wp;  dst = oWp;  }
        else { k -= 262144;                   src = Wq;  dst = oWq;  }
        float4 v = src[k];
        ushort4 u;
        u.x = f2bf(v.x); u.y = f2bf(v.y); u.z = f2bf(v.z); u.w = f2bf(v.w);
        dst[k] = u;
    }
}

__global__ __launch_bounds__(256) void k_init(
    const float* __restrict__ ef, const float* __restrict__ Wi,
    const float* __restrict__ bi, float* __restrict__ h0)
{
    __shared__ float efs[1024];
    int b = blockIdx.x, tid = threadIdx.x;
    for (int i = tid; i < 1024; i += 256) efs[i] = ef[(size_t)b * 1024 + i];
    __syncthreads();
    for (int j = tid; j < 512; j += 256) {
        const float4* w4 = (const float4*)(Wi + (size_t)j * 1024);
        float acc = 0.0f;
        for (int k4 = 0; k4 < 256; k4++) {
            float4 wv = w4[k4];
            int k = k4 << 2;
            acc = fmaf(efs[k],   wv.x, acc);
            acc = fmaf(efs[k+1], wv.y, acc);
            acc = fmaf(efs[k+2], wv.z, acc);
            acc = fmaf(efs[k+3], wv.w, acc);
        }
        h0[(size_t)b * 512 + j] = fast_tanh(acc + bi[j]);
    }
}

__global__ __launch_bounds__(512) void k_q0(
    const float* __restrict__ h, const float* __restrict__ Wq,
    float* __restrict__ qbuf)
{
    __shared__ float hs[512];
    int b = blockIdx.x, j = threadIdx.x;
    hs[j] = h[(size_t)b * 512 + j];
    __syncthreads();
    const float4* w4 = (const float4*)(Wq + (size_t)j * 512);
    float acc = 0.0f;
    #pragma unroll 4
    for (int k4 = 0; k4 < 128; k4++) {
        float4 wv = w4[k4];
        int k = k4 << 2;
        acc = fmaf(hs[k],   wv.x, acc);
        acc = fmaf(hs[k+1], wv.y, acc);
        acc = fmaf(hs[k+2], wv.z, acc);
        acc = fmaf(hs[k+3], wv.w, acc);
    }
    qbuf[(size_t)b * 512 + j] = acc;
}

// MFMA bf16 GEMM: C[M][N] = A[M][K] @ B[N][K]^T. (verified R2/R4/R7)
__global__ __launch_bounds__(256) void k_mfma_gemm(
    const float* __restrict__ Af,
    const unsigned short* __restrict__ A0, const unsigned short* __restrict__ A1,
    const unsigned short* __restrict__ A2,
    int ld0, int ld1, int ld2, int s1, int s2,
    const unsigned short* __restrict__ Bw, int ldb,
    float* __restrict__ Cf, unsigned short* __restrict__ Cb,
    unsigned char* __restrict__ C8, int ldc,
    const float* __restrict__ bias, int K)
{
    __shared__ __attribute__((aligned(16))) unsigned short As[128][40];
    __shared__ __attribute__((aligned(16))) unsigned short Bs[128][40];
    int m0 = blockIdx.x << 7, n0 = blockIdx.y << 7;
    int tid = threadIdx.x;
    int wave = tid >> 6, lane = tid & 63;
    int wr = (wave >> 1) << 6, wc = (wave & 1) << 6;
    int fr = lane & 15, fq = lane >> 4;
    f32x4 acc[4][4];
    #pragma unroll
    for (int i = 0; i < 4; i++)
        #pragma unroll
        for (int j = 0; j < 4; j++)
            acc[i][j] = (f32x4){0.f, 0.f, 0.f, 0.f};
    int lrow = tid >> 1;
    int lk = (tid & 1) << 4;
    for (int k0 = 0; k0 < K; k0 += 32) {
        u16x8 av0, av1;
        if (Af) {
            const float* ap = Af + (size_t)(m0 + lrow) * ld0 + k0 + lk;
            float4 f0 = *(const float4*)ap;
            float4 f1 = *(const float4*)(ap + 4);
            float4 f2 = *(const float4*)(ap + 8);
            float4 f3 = *(const float4*)(ap + 12);
            av0[0]=f2bf(f0.x); av0[1]=f2bf(f0.y); av0[2]=f2bf(f0.z); av0[3]=f2bf(f0.w);
            av0[4]=f2bf(f1.x); av0[5]=f2bf(f1.y); av0[6]=f2bf(f1.z); av0[7]=f2bf(f1.w);
            av1[0]=f2bf(f2.x); av1[1]=f2bf(f2.y); av1[2]=f2bf(f2.z); av1[3]=f2bf(f2.w);
            av1[4]=f2bf(f3.x); av1[5]=f2bf(f3.y); av1[6]=f2bf(f3.z); av1[7]=f2bf(f3.w);
        } else {
            const unsigned short* Ap; int lda_, ka;
            if (k0 < s1)      { Ap = A0; lda_ = ld0; ka = k0; }
            else if (k0 < s2) { Ap = A1; lda_ = ld1; ka = k0 - s1; }
            else              { Ap = A2; lda_ = ld2; ka = k0 - s2; }
            const unsigned short* ap = Ap + (size_t)(m0 + lrow) * lda_ + ka + lk;
            av0 = *(const u16x8*)ap;
            av1 = *(const u16x8*)(ap + 8);
        }
        const unsigned short* bp_ = Bw + (size_t)(n0 + lrow) * ldb + k0 + lk;
        u16x8 bv0 = *(const u16x8*)bp_;
        u16x8 bv1 = *(const u16x8*)(bp_ + 8);
        __syncthreads();
        *(u16x8*)&As[lrow][lk] = av0;
        *(u16x8*)&As[lrow][lk + 8] = av1;
        *(u16x8*)&Bs[lrow][lk] = bv0;
        *(u16x8*)&Bs[lrow][lk + 8] = bv1;
        __syncthreads();
        bf16x8 af[4], bf[4];
        #pragma unroll
        for (int i = 0; i < 4; i++) {
            af[i] = *(const bf16x8*)&As[wr + (i << 4) + fr][fq << 3];
            bf[i] = *(const bf16x8*)&Bs[wc + (i << 4) + fr][fq << 3];
        }
        #pragma unroll
        for (int i = 0; i < 4; i++)
            #pragma unroll
            for (int j = 0; j < 4; j++)
                acc[i][j] = __builtin_amdgcn_mfma_f32_16x16x32_bf16(af[i], bf[j], acc[i][j], 0, 0, 0);
    }
    #pragma unroll
    for (int j = 0; j < 4; j++) {
        int col = n0 + wc + (j << 4) + fr;
        float bv = bias ? bias[col] : 0.0f;
        #pragma unroll
        for (int i = 0; i < 4; i++) {
            int rbase = m0 + wr + (i << 4) + (fq << 2);
            #pragma unroll
            for (int r = 0; r < 4; r++) {
                float v = acc[i][j][r] + bv;
                if (C8)      C8[(size_t)(rbase + r) * ldc + col] = f2fp8(v);
                else if (Cb) Cb[(size_t)(rbase + r) * ldc + col] = f2bf(v);
                else         Cf[(size_t)(rbase + r) * ldc + col] = v;
            }
        }
    }
}

// ---------------- per-step kernel 1: attention (one block per batch) -------
// 64 blocks x 512 thr. Full 400-s softmax in-block (exact), writes combined
// normalized ctx (bf16) directly to csb[b][t][0..1023].
__global__ __launch_bounds__(512) void k_attn3(
    const unsigned char* __restrict__ pkb8, const unsigned char* __restrict__ ehb8,
    const float* __restrict__ qbuf, const float* __restrict__ qpart,
    const float* __restrict__ We,
    unsigned short* __restrict__ csb, int t)
{
    int b = blockIdx.x;
    int tid = threadIdx.x, wave = tid >> 6, lane = tid & 63;
    __shared__ float qS[512];
    __shared__ float eL[400], pL[400];
    __shared__ float rbuf[512];
    __shared__ float cbuf[1024];

    if (t == 0) {
        qS[tid] = qbuf[(size_t)b * 512 + tid];
    } else {
        float s = 0.0f;
        #pragma unroll
        for (int cc = 0; cc < 8; cc++)
            s += qpart[(((size_t)(cc * 64 + b)) << 9) + tid];
        qS[tid] = s;
    }
    __syncthreads();

    float q8[8], w8[8];
    {
        #pragma unroll
        for (int jj = 0; jj < 8; jj++) q8[jj] = qS[(lane << 3) + jj];
        const float4* wp = (const float4*)(We + (lane << 3));
        float4 w0 = wp[0], w1 = wp[1];
        w8[0]=w0.x; w8[1]=w0.y; w8[2]=w0.z; w8[3]=w0.w;
        w8[4]=w1.x; w8[5]=w1.y; w8[6]=w1.z; w8[7]=w1.w;
    }
    // energies: 8 waves x 50 rows
    for (int sl = wave; sl < Sdim; sl += 8) {
        const unsigned char* pr = pkb8 + ((size_t)(b * Sdim + sl) << 9) + (lane << 3);
        uint2 u = *(const uint2*)pr;
        float p[8];
        dec4(u.x, p); dec4(u.y, p + 4);
        float sum = 0.0f;
        #pragma unroll
        for (int jj = 0; jj < 8; jj++)
            sum = fmaf(fast_tanh(q8[jj] + p[jj]), w8[jj], sum);
        #pragma unroll
        for (int off = 32; off > 0; off >>= 1) sum += __shfl_xor(sum, off, 64);
        if (lane == 0) eL[sl] = sum;
    }
    __syncthreads();
    // exact softmax over 400
    float e = (tid < Sdim) ? eL[tid] : -3.0e38f;
    rbuf[tid] = e; __syncthreads();
    for (int st = 256; st > 0; st >>= 1) {
        if (tid < st) rbuf[tid] = fmaxf(rbuf[tid], rbuf[tid + st]);
        __syncthreads();
    }
    float mx = rbuf[0];
    __syncthreads();
    float p = (tid < Sdim) ? __expf(e - mx) : 0.0f;
    if (tid < Sdim) pL[tid] = p;
    rbuf[tid] = p; __syncthreads();
    for (int st = 256; st > 0; st >>= 1) {
        if (tid < st) rbuf[tid] += rbuf[tid + st];
        __syncthreads();
    }
    float inv = 1.0f / rbuf[0];
    __syncthreads();
    // context: 2 row-groups x 256 thr x 4 dims
    int g = tid >> 8, d0 = (tid & 255) << 2;
    float a0 = 0.f, a1 = 0.f, a2 = 0.f, a3 = 0.f;
    const unsigned char* eb = ehb8 + ((size_t)(b * Sdim) << 10) + d0;
    #pragma unroll 4
    for (int sl = g; sl < Sdim; sl += 2) {
        float pp = pL[sl];
        unsigned int u = *(const unsigned int*)(eb + ((size_t)sl << 10));
        float v[4];
        dec4(u, v);
        a0 = fmaf(pp, v[0], a0);
        a1 = fmaf(pp, v[1], a1);
        a2 = fmaf(pp, v[2], a2);
        a3 = fmaf(pp, v[3], a3);
    }
    if (g) { cbuf[d0] = a0; cbuf[d0+1] = a1; cbuf[d0+2] = a2; cbuf[d0+3] = a3; }
    __syncthreads();
    if (!g) {
        a0 = (a0 + cbuf[d0])   * inv;
        a1 = (a1 + cbuf[d0+1]) * inv;
        a2 = (a2 + cbuf[d0+2]) * inv;
        a3 = (a3 + cbuf[d0+3]) * inv;
        ushort4 u;
        u.x = f2bf(a0); u.y = f2bf(a1); u.z = f2bf(a2); u.w = f2bf(a3);
        *(ushort4*)&csb[(((size_t)(b * Tdim + t)) << 10) + d0] = u;
    }
}

// ---------------- per-step kernel 2: GRU + gates + q-partials ---------------
// 32 blocks x 256 thr: bid = mb*8 + c, mb in [0,4) = 16-batch group,
// c in [0,8) = 64-wide j-slice. Full-K MFMA (gi: csb K=1024; gh: h K=512),
// gate-coupled per wave (frags {w, w+4, w+8} = 3 gates of jj16 group w),
// gates in registers -> h(t) -> qpart[c] rows mb0..mb0+16.
__global__ __launch_bounds__(256) void k_gru2(
    const unsigned short* __restrict__ csb,
    const float* __restrict__ hb_old, float* __restrict__ hb_new,
    const unsigned short* __restrict__ Wihb, const unsigned short* __restrict__ Whhb,
    const unsigned short* __restrict__ Wqb, const unsigned short* __restrict__ giEb,
    const float* __restrict__ bih, const float* __restrict__ bhh,
    float* __restrict__ qpart, unsigned short* __restrict__ dsb,
    float* __restrict__ ds, float* __restrict__ hlast, int t, int last)
{
    __shared__ __attribute__((aligned(16))) unsigned short As[16][72];
    __shared__ __attribute__((aligned(16))) unsigned short Ws[192][72];
    int bid = blockIdx.x;
    int mb0 = (bid >> 3) << 4;      // batch group base
    int c = bid & 7, j0 = c << 6;   // j-slice base
    int tid = threadIdx.x, wave = tid >> 6, lane = tid & 63;
    int fr = lane & 15, fq = lane >> 4;

    f32x4 gacc[3], hacc[3];
    #pragma unroll
    for (int g = 0; g < 3; g++) {
        gacc[g] = (f32x4){0.f,0.f,0.f,0.f};
        hacc[g] = (f32x4){0.f,0.f,0.f,0.f};
    }

    // ---- gi (ctx part): K=1024, 16 chunks of 64 ----
    for (int kc = 0; kc < 16; kc++) {
        __syncthreads();
        if (tid < 128) {           // stage As: 16 rows x 64 k (bf16 copy)
            int row = tid >> 3, colg = (tid & 7) << 3;
            *(u16x8*)&As[row][colg] =
                *(const u16x8*)(csb + (((size_t)((mb0 + row) * Tdim + t)) << 10) + (kc << 6) + colg);
        }
        #pragma unroll
        for (int it = 0; it < 6; it++) {   // stage Ws: 192 gate-rows x 64 k
            int idx = tid + (it << 8);
            int row = idx >> 3, colg = (idx & 7) << 3;
            int g = row >> 6, jj = row & 63;
            *(u16x8*)&Ws[row][colg] =
                *(const u16x8*)(Wihb + ((size_t)(g * 512 + j0 + jj)) * H3 + 512 + (kc << 6) + colg);
        }
        __syncthreads();
        #pragma unroll
        for (int s = 0; s < 2; s++) {
            bf16x8 af = *(const bf16x8*)&As[fr][(s << 5) + (fq << 3)];
            #pragma unroll
            for (int g = 0; g < 3; g++) {
                bf16x8 bf = *(const bf16x8*)&Ws[(g << 6) + (wave << 4) + fr][(s << 5) + (fq << 3)];
                gacc[g] = __builtin_amdgcn_mfma_f32_16x16x32_bf16(af, bf, gacc[g], 0, 0, 0);
            }
        }
    }

    // ---- gh: K=512, 8 chunks of 64 ----
    for (int kc = 0; kc < 8; kc++) {
        __syncthreads();
        if (tid < 128) {           // stage As: h_old f32 -> bf16
            int row = tid >> 3, colg = (tid & 7) << 3;
            const float* p = hb_old + (size_t)(mb0 + row) * 512 + (kc << 6) + colg;
            float4 v0 = *(const float4*)p;
            float4 v1 = *(const float4*)(p + 4);
            u16x8 u;
            u[0]=f2bf(v0.x); u[1]=f2bf(v0.y); u[2]=f2bf(v0.z); u[3]=f2bf(v0.w);
            u[4]=f2bf(v1.x); u[5]=f2bf(v1.y); u[6]=f2bf(v1.z); u[7]=f2bf(v1.w);
            *(u16x8*)&As[row][colg] = u;
        }
        #pragma unroll
        for (int it = 0; it < 6; it++) {
            int idx = tid + (it << 8);
            int row = idx >> 3, colg = (idx & 7) << 3;
            int g = row >> 6, jj = row & 63;
            *(u16x8*)&Ws[row][colg] =
                *(const u16x8*)(Whhb + ((size_t)(g * 512 + j0 + jj)) * Hdim + (kc << 6) + colg);
        }
        __syncthreads();
        #pragma unroll
        for (int s = 0; s < 2; s++) {
            bf16x8 af = *(const bf16x8*)&As[fr][(s << 5) + (fq << 3)];
            #pragma unroll
            for (int g = 0; g < 3; g++) {
                bf16x8 bf = *(const bf16x8*)&Ws[(g << 6) + (wave << 4) + fr][(s << 5) + (fq << 3)];
                hacc[g] = __builtin_amdgcn_mfma_f32_16x16x32_bf16(af, bf, hacc[g], 0, 0, 0);
            }
        }
    }

    // ---- gates in registers; write h(t); stage h_new into As ----
    __syncthreads();
    {
        int j = j0 + (wave << 4) + fr;
        float bi0 = bih[j], bi1 = bih[512 + j], bi2 = bih[1024 + j];
        float bh0 = bhh[j], bh1 = bhh[512 + j], bh2 = bhh[1024 + j];
        #pragma unroll
        for (int r4 = 0; r4 < 4; r4++) {
            int b = mb0 + (fq << 2) + r4;
            size_t m = (size_t)b * Tdim + t;
            const unsigned short* ge = giEb + m * H3;
            float gi0 = gacc[0][r4] + bf2f(ge[j])        + bi0;
            float gi1 = gacc[1][r4] + bf2f(ge[512 + j])  + bi1;
            float gi2 = gacc[2][r4] + bf2f(ge[1024 + j]) + bi2;
            float gh0 = hacc[0][r4] + bh0;
            float gh1 = hacc[1][r4] + bh1;
            float gh2 = hacc[2][r4] + bh2;
            float rg = sigm(gi0 + gh0);
            float zz = sigm(gi1 + gh1);
            float nn = fast_tanh(gi2 + rg * gh2);
            float hold = hb_old[(size_t)b * 512 + j];
            float hn = (1.0f - zz) * nn + zz * hold;
            hb_new[(size_t)b * 512 + j] = hn;
            ds[m * 512 + j] = hn;
            dsb[m * 512 + j] = f2bf(hn);
            if (last) hlast[(size_t)b * 512 + j] = hn;
            As[(fq << 2) + r4][(wave << 4) + fr] = f2bf(hn);   // hS[b-mb0][jj]
        }
    }

    // ---- qpart[c] rows mb0..mb0+16 = h_new_slice @ Wq[:, slice]^T ----
    for (int ch = 0; ch < 4; ch++) {
        __syncthreads();
        #pragma unroll
        for (int it = 0; it < 4; it++) {   // stage Wq: 128 rows x 64 k
            int idx = tid + (it << 8);
            int row = idx >> 3, colg = (idx & 7) << 3;
            *(u16x8*)&Ws[row][colg] =
                *(const u16x8*)(Wqb + ((size_t)(ch * 128 + row)) * 512 + j0 + colg);
        }
        __syncthreads();
        f32x4 qa[2];
        qa[0] = (f32x4){0.f,0.f,0.f,0.f};
        qa[1] = (f32x4){0.f,0.f,0.f,0.f};
        #pragma unroll
        for (int s = 0; s < 2; s++) {
            bf16x8 af = *(const bf16x8*)&As[fr][(s << 5) + (fq << 3)];
            #pragma unroll
            for (int u = 0; u < 2; u++) {
                bf16x8 bf = *(const bf16x8*)&Ws[((wave + (u << 2)) << 4) + fr][(s << 5) + (fq << 3)];
                qa[u] = __builtin_amdgcn_mfma_f32_16x16x32_bf16(af, bf, qa[u], 0, 0, 0);
            }
        }
        #pragma unroll
        for (int u = 0; u < 2; u++) {
            int jq = (ch << 7) + ((wave + (u << 2)) << 4) + fr;
            #pragma unroll
            for (int r4 = 0; r4 < 4; r4++) {
                int b = mb0 + (fq << 2) + r4;
                qpart[(((size_t)(c * 64 + b)) << 9) + jq] = qa[u][r4];
            }
        }
    }
}

extern "C" void kernel_launch(void* const* d_in, const int* in_sizes, int n_in,
                              void* d_out, int out_size, void* d_ws, size_t ws_size,
                              hipStream_t stream) {
    const float* te  = (const float*)d_in[0];
    const float* eh  = (const float*)d_in[1];
    const float* ef  = (const float*)d_in[2];
    const float* Wi  = (const float*)d_in[3];
    const float* bi  = (const float*)d_in[4];
    const float* Wk  = (const float*)d_in[5];
    const float* Wq  = (const float*)d_in[6];
    const float* We  = (const float*)d_in[7];
    const float* Wih = (const float*)d_in[8];
    const float* Whh = (const float*)d_in[9];
    const float* bih = (const float*)d_in[10];
    const float* bhh = (const float*)d_in[11];
    const float* Wp  = (const float*)d_in[12];
    const float* bp  = (const float*)d_in[13];

    float* out     = (float*)d_out;
    float* out_ds  = out;
    float* out_hl  = out + (size_t)Bdim * Tdim * Hdim;
    float* out_pre = out_hl + (size_t)Bdim * Hdim;

    // ---- workspace ----
    char* w = (char*)d_ws;
    size_t o = 0;
    unsigned char*  pkb8 = (unsigned char*)(w + o);  o += (size_t)25600 * 512;
    unsigned char*  ehb8 = (unsigned char*)(w + o);  o += (size_t)25600 * 1024;
    unsigned short* teb  = (unsigned short*)(w + o); o += (size_t)6400 * 512 * 2;
    unsigned short* Wkb  = (unsigned short*)(w + o); o += (size_t)512 * 1024 * 2;
    unsigned short* Wihb = (unsigned short*)(w + o); o += (size_t)1536 * 1536 * 2;
    unsigned short* Whhb = (unsigned short*)(w + o); o += (size_t)1536 * 512 * 2;
    unsigned short* Wpb  = (unsigned short*)(w + o); o += (size_t)512 * 2048 * 2;
    unsigned short* Wqb  = (unsigned short*)(w + o); o += (size_t)512 * 512 * 2;
    unsigned short* dsb  = (unsigned short*)(w + o); o += (size_t)6400 * 512 * 2;
    unsigned short* csb  = (unsigned short*)(w + o); o += (size_t)6400 * 1024 * 2;
    unsigned short* giEb = (unsigned short*)(w + o); o += (size_t)6400 * 1536 * 2;
    float* qbuf  = (float*)(w + o); o += (size_t)Bdim * 512 * 4;
    float* hbuf  = (float*)(w + o); o += (size_t)2 * Bdim * 512 * 4;   // ping-pong
    float* qpart = (float*)(w + o); o += (size_t)8 * Bdim * 512 * 4;

    // ---- one-time prep (7 dispatches) ----
    k_cvt8<<<2048, 256, 0, stream>>>((const float4*)eh, (uchar4*)ehb8, 6553600);
    k_cvt<<<512, 256, 0, stream>>>((const float4*)te, (ushort4*)teb, 819200);
    k_cvtW<<<1024, 256, 0, stream>>>(
        (const float4*)Wk, (const float4*)Wih, (const float4*)Whh,
        (const float4*)Wp, (const float4*)Wq,
        (ushort4*)Wkb, (ushort4*)Wihb, (ushort4*)Whhb, (ushort4*)Wpb, (ushort4*)Wqb);
    k_init<<<Bdim, 256, 0, stream>>>(ef, Wi, bi, hbuf);
    k_q0<<<Bdim, 512, 0, stream>>>(hbuf, Wq, qbuf);
    // proj_key = eh(f32) @ Wkb^T -> pkb8 (fp8), M=25600 N=512 K=1024
    k_mfma_gemm<<<dim3(200, 4), 256, 0, stream>>>(
        eh, nullptr, nullptr, nullptr, 1024, 0, 0, 1024, 1024,
        Wkb, 1024, nullptr, nullptr, pkb8, 512, nullptr, 1024);
    // gi_embed = teb @ Wihb[:, :512]^T -> giEb (bf16), M=6400 N=1536 K=512
    k_mfma_gemm<<<dim3(50, 12), 256, 0, stream>>>(
        nullptr, teb, teb, teb, 512, 512, 512, 512, 512,
        Wihb, 1536, nullptr, giEb, nullptr, 1536, nullptr, 512);

    // ---- scan: 2 wide dispatches per step ----
    for (int t = 0; t < Tdim; t++) {
        float* hb_old = hbuf + (size_t)(t & 1) * 32768;
        float* hb_new = hbuf + (size_t)((t + 1) & 1) * 32768;
        k_attn3<<<Bdim, 512, 0, stream>>>(pkb8, ehb8, qbuf, qpart, We, csb, t);
        k_gru2<<<32, 256, 0, stream>>>(csb, hb_old, hb_new,
                                       Wihb, Whhb, Wqb, giEb, bih, bhh,
                                       qpart, dsb, out_ds, out_hl,
                                       t, (t == Tdim - 1) ? 1 : 0);
    }

    // ---- final: pre = [teb | dsb | csb] @ Wpb^T + bp, M=6400 N=512 K=2048 ----
    k_mfma_gemm<<<dim3(50, 4), 256, 0, stream>>>(
        nullptr, teb, dsb, csb, 512, 512, 1024, 512, 1024,
        Wpb, 2048, out_pre, nullptr, nullptr, 512, bp, 2048);
}

// Round 9
// 7059.071 us; speedup vs baseline: 1.4531x; 1.3482x over previous
//
#include <hip/hip_runtime.h>
#include <cstddef>

// Decoder: B=64, S=400, T=100, E=512, H=512
// R9: 2 WIDE dispatches/step. KA (512 blk) = R4 k_gates fused into R7 k_attn2:
// gates->h->q(packed-fp8 GEMV) then energies/softmax/ctx-partials.
// KB (144 blk) = R4 k_mm verbatim + R7 online-softmax combine weights.
// k_gfin computes final gates after the loop. Lesson from R7/R8: dispatch
// overhead ~17us matters, but every kernel must also be wide (>=144 blocks).

#define Bdim 64
#define Sdim 400
#define Tdim 100
#define Edim 512
#define Hdim 512
#define H2   1024
#define H3   1536

typedef __attribute__((ext_vector_type(8))) short          bf16x8;
typedef __attribute__((ext_vector_type(8))) unsigned short u16x8;
typedef __attribute__((ext_vector_type(4))) float          f32x4;

__device__ __forceinline__ float bf2f(unsigned short u) {
    return __uint_as_float(((unsigned int)u) << 16);
}
__device__ __forceinline__ unsigned short f2bf(float f) {
    unsigned int x = __float_as_uint(f);
    x += 0x7fffu + ((x >> 16) & 1u);
    return (unsigned short)(x >> 16);
}
__device__ __forceinline__ float fast_tanh(float x) {
    float e = __expf(2.0f * x);
    return 1.0f - 2.0f / (e + 1.0f);
}
__device__ __forceinline__ float sigm(float x) {
    return 1.0f / (1.0f + __expf(-x));
}

// ---- OCP e4m3fn encode ----
__device__ __forceinline__ unsigned char f2fp8(float f) {
    unsigned u = __float_as_uint(f);
    unsigned s = (u >> 24) & 0x80u;
    float a = fabsf(f);
    if (a >= 448.0f) return (unsigned char)(s | 0x7Eu);
    if (a < 0.0009765625f) return (unsigned char)s;
    int e = (int)((u >> 23) & 0xFF) - 127;
    if (e < -6) {
        int q = (int)lrintf(a * 512.0f);
        return (unsigned char)(s | (unsigned)q);
    }
    unsigned mant = u & 0x7FFFFFu;
    unsigned keep = mant >> 20;
    unsigned rem  = mant & 0xFFFFFu;
    if (rem > 0x80000u || (rem == 0x80000u && (keep & 1u))) keep++;
    if (keep == 8u) { keep = 0u; e++; if (e > 8) return (unsigned char)(s | 0x7Eu); }
    return (unsigned char)(s | ((unsigned)(e + 7) << 3) | keep);
}

#if defined(__has_builtin)
#if __has_builtin(__builtin_amdgcn_cvt_pk_f32_fp8)
#define HWFP8 1
#endif
#endif
__device__ __forceinline__ float fp8sw(unsigned char v) {
    unsigned e = (v >> 3) & 15u, m = v & 7u, s = v >> 7;
    float f = e ? __uint_as_float(((e + 120u) << 23) | (m << 20))
                : (float)m * 0.001953125f;
    return s ? -f : f;
}
__device__ __forceinline__ void dec4(unsigned int w, float* o) {
#ifdef HWFP8
    auto lo = __builtin_amdgcn_cvt_pk_f32_fp8(w, false);
    auto hi = __builtin_amdgcn_cvt_pk_f32_fp8(w, true);
    o[0] = lo[0]; o[1] = lo[1]; o[2] = hi[0]; o[3] = hi[1];
#else
    o[0] = fp8sw(w & 0xFF); o[1] = fp8sw((w >> 8) & 0xFF);
    o[2] = fp8sw((w >> 16) & 0xFF); o[3] = fp8sw(w >> 24);
#endif
}

// ---------------- one-time kernels ----------------

__global__ void k_cvt(const float4* __restrict__ in, ushort4* __restrict__ out, int n4) {
    int i = blockIdx.x * blockDim.x + threadIdx.x;
    int stride = gridDim.x * blockDim.x;
    for (; i < n4; i += stride) {
        float4 v = in[i];
        ushort4 u;
        u.x = f2bf(v.x); u.y = f2bf(v.y); u.z = f2bf(v.z); u.w = f2bf(v.w);
        out[i] = u;
    }
}

__global__ void k_cvt8(const float4* __restrict__ in, uchar4* __restrict__ out, int n4) {
    int i = blockIdx.x * blockDim.x + threadIdx.x;
    int stride = gridDim.x * blockDim.x;
    for (; i < n4; i += stride) {
        float4 v = in[i];
        uchar4 u;
        u.x = f2fp8(v.x); u.y = f2fp8(v.y); u.z = f2fp8(v.z); u.w = f2fp8(v.w);
        out[i] = u;
    }
}

__global__ void k_cvtW(
    const float4* __restrict__ Wk, const float4* __restrict__ Wih,
    const float4* __restrict__ Whh, const float4* __restrict__ Wp,
    ushort4* __restrict__ oWk, ushort4* __restrict__ oWih,
    ushort4* __restrict__ oWhh, ushort4* __restrict__ oWp)
{
    int i = blockIdx.x * blockDim.x + threadIdx.x;
    int stride = gridDim.x * blockDim.x;
    for (; i < 1179648; i += stride) {
        const float4* src; ushort4* dst; int k = i;
        if (k < 131072)                     { src = Wk;  dst = oWk;  }
        else if ((k -= 131072) < 589824)    { src = Wih; dst = oWih; }
        else if ((k -= 589824) < 196608)    { src = Whh; dst = oWhh; }
        else { k -= 196608;                   src = Wp;  dst = oWp;  }
        float4 v = src[k];
        ushort4 u;
        u.x = f2bf(v.x); u.y = f2bf(v.y); u.z = f2bf(v.z); u.w = f2bf(v.w);
        dst[k] = u;
    }
}

// pack Wq into k4-major fp8: Wq8p[(k4*512 + j)*4 + kk] = fp8(Wq[j][4*k4+kk])
__global__ __launch_bounds__(256) void k_packWq(
    const float* __restrict__ Wq, uchar4* __restrict__ Wq8p)
{
    int i = blockIdx.x * 256 + threadIdx.x;     // 65536 uchar4 elements
    if (i >= 65536) return;
    int k4 = i >> 9, j = i & 511;
    const float* src = Wq + (size_t)j * 512 + (k4 << 2);
    uchar4 u;
    u.x = f2fp8(src[0]); u.y = f2fp8(src[1]);
    u.z = f2fp8(src[2]); u.w = f2fp8(src[3]);
    Wq8p[i] = u;
}

__global__ __launch_bounds__(256) void k_init(
    const float* __restrict__ ef, const float* __restrict__ Wi,
    const float* __restrict__ bi, float* __restrict__ h0,
    unsigned short* __restrict__ hb16)
{
    __shared__ float efs[1024];
    int b = blockIdx.x, tid = threadIdx.x;
    for (int i = tid; i < 1024; i += 256) efs[i] = ef[(size_t)b * 1024 + i];
    __syncthreads();
    for (int j = tid; j < 512; j += 256) {
        const float4* w4 = (const float4*)(Wi + (size_t)j * 1024);
        float acc = 0.0f;
        for (int k4 = 0; k4 < 256; k4++) {
            float4 wv = w4[k4];
            int k = k4 << 2;
            acc = fmaf(efs[k],   wv.x, acc);
            acc = fmaf(efs[k+1], wv.y, acc);
            acc = fmaf(efs[k+2], wv.z, acc);
            acc = fmaf(efs[k+3], wv.w, acc);
        }
        float h = fast_tanh(acc + bi[j]);
        h0[(size_t)b * 512 + j] = h;
        hb16[(size_t)b * 512 + j] = f2bf(h);
    }
}

__global__ __launch_bounds__(512) void k_q0(
    const float* __restrict__ h, const float* __restrict__ Wq,
    float* __restrict__ qbuf)
{
    __shared__ float hs[512];
    int b = blockIdx.x, j = threadIdx.x;
    hs[j] = h[(size_t)b * 512 + j];
    __syncthreads();
    const float4* w4 = (const float4*)(Wq + (size_t)j * 512);
    float acc = 0.0f;
    #pragma unroll 4
    for (int k4 = 0; k4 < 128; k4++) {
        float4 wv = w4[k4];
        int k = k4 << 2;
        acc = fmaf(hs[k],   wv.x, acc);
        acc = fmaf(hs[k+1], wv.y, acc);
        acc = fmaf(hs[k+2], wv.z, acc);
        acc = fmaf(hs[k+3], wv.w, acc);
    }
    qbuf[(size_t)b * 512 + j] = acc;
}

// MFMA bf16 GEMM: C[M][N] = A[M][K] @ B[N][K]^T. (verified R2/R4/R7/R8)
__global__ __launch_bounds__(256) void k_mfma_gemm(
    const float* __restrict__ Af,
    const unsigned short* __restrict__ A0, const unsigned short* __restrict__ A1,
    const unsigned short* __restrict__ A2,
    int ld0, int ld1, int ld2, int s1, int s2,
    const unsigned short* __restrict__ Bw, int ldb,
    float* __restrict__ Cf, unsigned short* __restrict__ Cb,
    unsigned char* __restrict__ C8, int ldc,
    const float* __restrict__ bias, int K)
{
    __shared__ __attribute__((aligned(16))) unsigned short As[128][40];
    __shared__ __attribute__((aligned(16))) unsigned short Bs[128][40];
    int m0 = blockIdx.x << 7, n0 = blockIdx.y << 7;
    int tid = threadIdx.x;
    int wave = tid >> 6, lane = tid & 63;
    int wr = (wave >> 1) << 6, wc = (wave & 1) << 6;
    int fr = lane & 15, fq = lane >> 4;
    f32x4 acc[4][4];
    #pragma unroll
    for (int i = 0; i < 4; i++)
        #pragma unroll
        for (int j = 0; j < 4; j++)
            acc[i][j] = (f32x4){0.f, 0.f, 0.f, 0.f};
    int lrow = tid >> 1;
    int lk = (tid & 1) << 4;
    for (int k0 = 0; k0 < K; k0 += 32) {
        u16x8 av0, av1;
        if (Af) {
            const float* ap = Af + (size_t)(m0 + lrow) * ld0 + k0 + lk;
            float4 f0 = *(const float4*)ap;
            float4 f1 = *(const float4*)(ap + 4);
            float4 f2 = *(const float4*)(ap + 8);
            float4 f3 = *(const float4*)(ap + 12);
            av0[0]=f2bf(f0.x); av0[1]=f2bf(f0.y); av0[2]=f2bf(f0.z); av0[3]=f2bf(f0.w);
            av0[4]=f2bf(f1.x); av0[5]=f2bf(f1.y); av0[6]=f2bf(f1.z); av0[7]=f2bf(f1.w);
            av1[0]=f2bf(f2.x); av1[1]=f2bf(f2.y); av1[2]=f2bf(f2.z); av1[3]=f2bf(f2.w);
            av1[4]=f2bf(f3.x); av1[5]=f2bf(f3.y); av1[6]=f2bf(f3.z); av1[7]=f2bf(f3.w);
        } else {
            const unsigned short* Ap; int lda_, ka;
            if (k0 < s1)      { Ap = A0; lda_ = ld0; ka = k0; }
            else if (k0 < s2) { Ap = A1; lda_ = ld1; ka = k0 - s1; }
            else              { Ap = A2; lda_ = ld2; ka = k0 - s2; }
            const unsigned short* ap = Ap + (size_t)(m0 + lrow) * lda_ + ka + lk;
            av0 = *(const u16x8*)ap;
            av1 = *(const u16x8*)(ap + 8);
        }
        const unsigned short* bp_ = Bw + (size_t)(n0 + lrow) * ldb + k0 + lk;
        u16x8 bv0 = *(const u16x8*)bp_;
        u16x8 bv1 = *(const u16x8*)(bp_ + 8);
        __syncthreads();
        *(u16x8*)&As[lrow][lk] = av0;
        *(u16x8*)&As[lrow][lk + 8] = av1;
        *(u16x8*)&Bs[lrow][lk] = bv0;
        *(u16x8*)&Bs[lrow][lk + 8] = bv1;
        __syncthreads();
        bf16x8 af[4], bf[4];
        #pragma unroll
        for (int i = 0; i < 4; i++) {
            af[i] = *(const bf16x8*)&As[wr + (i << 4) + fr][fq << 3];
            bf[i] = *(const bf16x8*)&Bs[wc + (i << 4) + fr][fq << 3];
        }
        #pragma unroll
        for (int i = 0; i < 4; i++)
            #pragma unroll
            for (int j = 0; j < 4; j++)
                acc[i][j] = __builtin_amdgcn_mfma_f32_16x16x32_bf16(af[i], bf[j], acc[i][j], 0, 0, 0);
    }
    #pragma unroll
    for (int j = 0; j < 4; j++) {
        int col = n0 + wc + (j << 4) + fr;
        float bv = bias ? bias[col] : 0.0f;
        #pragma unroll
        for (int i = 0; i < 4; i++) {
            int rbase = m0 + wr + (i << 4) + (fq << 2);
            #pragma unroll
            for (int r = 0; r < 4; r++) {
                float v = acc[i][j][r] + bv;
                if (C8)      C8[(size_t)(rbase + r) * ldc + col] = f2fp8(v);
                else if (Cb) Cb[(size_t)(rbase + r) * ldc + col] = f2bf(v);
                else         Cf[(size_t)(rbase + r) * ldc + col] = v;
            }
        }
    }
}

// ---------------- per-step kernel A: gates+q+attention ----------------
// 512 blocks x 256 thr; b = bid>>3, sc = bid&7 (8 s-chunks of 50).
// t>0: reduce pgi/pgh(t-1) -> gates -> S_t (sc==0 writes ds/h/hb16) ->
// q_t via packed fp8 Wq GEMV. Then energies/softmax-stats/ctx-partials (R7).
__global__ __launch_bounds__(256) void k_attn4(
    const unsigned char* __restrict__ pkb8, const unsigned char* __restrict__ ehb8,
    const float* __restrict__ qbuf,
    const float* __restrict__ pgi, const float* __restrict__ pgh,
    const unsigned short* __restrict__ giEb,
    const float* __restrict__ bih, const float* __restrict__ bhh,
    const float* __restrict__ hb_old, float* __restrict__ hb_new,
    unsigned short* __restrict__ hb16,
    const unsigned char* __restrict__ Wq8p, const float* __restrict__ We,
    float* __restrict__ ctxp, float* __restrict__ mcb, float* __restrict__ sumc,
    float* __restrict__ ds, unsigned short* __restrict__ dsb, int t)
{
    int bid = blockIdx.x;
    int b = bid >> 3, sc = bid & 7;
    int s0 = sc * 50;
    int tid = threadIdx.x, wave = tid >> 6, lane = tid & 63;
    __shared__ float qS[512], hS[512];
    __shared__ float eL[52], pL[52];

    if (t == 0) {
        qS[tid]       = qbuf[(size_t)b * 512 + tid];
        qS[tid + 256] = qbuf[(size_t)b * 512 + tid + 256];
    } else {
        // gates for batch b (full 512 j; redundant across the 8 sc-blocks)
        for (int jj = tid; jj < 512; jj += 256) {
            float gi0 = 0, gi1 = 0, gi2 = 0, gh0 = 0, gh1 = 0, gh2 = 0;
            #pragma unroll
            for (int cc = 0; cc < 4; cc++) {
                const float* p = pgi + ((size_t)(cc * 64 + b)) * H3;
                gi0 += p[jj]; gi1 += p[jj + 512]; gi2 += p[jj + 1024];
            }
            #pragma unroll
            for (int cc = 0; cc < 2; cc++) {
                const float* p = pgh + ((size_t)(cc * 64 + b)) * H3;
                gh0 += p[jj]; gh1 += p[jj + 512]; gh2 += p[jj + 1024];
            }
            size_t m = (size_t)b * Tdim + (t - 1);
            const unsigned short* ge = giEb + m * H3;
            gi0 += bf2f(ge[jj])        + bih[jj];
            gi1 += bf2f(ge[jj + 512])  + bih[jj + 512];
            gi2 += bf2f(ge[jj + 1024]) + bih[jj + 1024];
            gh0 += bhh[jj]; gh1 += bhh[jj + 512]; gh2 += bhh[jj + 1024];
            float rg = sigm(gi0 + gh0);
            float zz = sigm(gi1 + gh1);
            float nn = fast_tanh(gi2 + rg * gh2);
            float hold = hb_old[(size_t)b * 512 + jj];
            float hn = (1.0f - zz) * nn + zz * hold;
            hS[jj] = hn;
            if (sc == 0) {
                hb_new[(size_t)b * 512 + jj] = hn;
                hb16[(size_t)b * 512 + jj] = f2bf(hn);
                ds[m * 512 + jj] = hn;
                dsb[m * 512 + jj] = f2bf(hn);
            }
        }
        __syncthreads();
        // q_t[jj] = sum_k hS[k] * Wq[jj][k]  (fp8 packed, k4-major -> coalesced)
        for (int jj = tid; jj < 512; jj += 256) {
            float acc = 0.0f;
            const unsigned int* wp = (const unsigned int*)Wq8p + jj;
            #pragma unroll 4
            for (int k4 = 0; k4 < 128; k4++) {
                float4 hv = *(const float4*)&hS[k4 << 2];
                unsigned int wv = wp[(size_t)k4 << 9];
                float d[4];
                dec4(wv, d);
                acc = fmaf(hv.x, d[0], acc);
                acc = fmaf(hv.y, d[1], acc);
                acc = fmaf(hv.z, d[2], acc);
                acc = fmaf(hv.w, d[3], acc);
            }
            qS[jj] = acc;
        }
    }
    __syncthreads();

    float q8[8], w8[8];
    {
        #pragma unroll
        for (int jj = 0; jj < 8; jj++) q8[jj] = qS[(lane << 3) + jj];
        const float4* wp = (const float4*)(We + (lane << 3));
        float4 w0 = wp[0], w1 = wp[1];
        w8[0]=w0.x; w8[1]=w0.y; w8[2]=w0.z; w8[3]=w0.w;
        w8[4]=w1.x; w8[5]=w1.y; w8[6]=w1.z; w8[7]=w1.w;
    }
    // energies, one wave per s row
    for (int sl = wave; sl < 50; sl += 4) {
        const unsigned char* pr = pkb8 + ((size_t)(b * Sdim + s0 + sl) << 9) + (lane << 3);
        uint2 u = *(const uint2*)pr;
        float p[8];
        dec4(u.x, p); dec4(u.y, p + 4);
        float sum = 0.0f;
        #pragma unroll
        for (int jj = 0; jj < 8; jj++)
            sum = fmaf(fast_tanh(q8[jj] + p[jj]), w8[jj], sum);
        #pragma unroll
        for (int off = 32; off > 0; off >>= 1) sum += __shfl_xor(sum, off, 64);
        if (lane == 0) eL[sl] = sum;
    }
    __syncthreads();
    // chunk-local softmax stats with max subtraction
    if (wave == 0) {
        float ev = (lane < 50) ? eL[lane] : -3.0e38f;
        float mx = ev;
        #pragma unroll
        for (int off = 32; off > 0; off >>= 1) mx = fmaxf(mx, __shfl_xor(mx, off, 64));
        float pv = (lane < 50) ? __expf(ev - mx) : 0.0f;
        if (lane < 50) pL[lane] = pv;
        float s = pv;
        #pragma unroll
        for (int off = 32; off > 0; off >>= 1) s += __shfl_xor(s, off, 64);
        if (lane == 0) { mcb[b * 8 + sc] = mx; sumc[b * 8 + sc] = s; }
    }
    __syncthreads();
    // unnormalized context partial; thread owns 4 dims
    int d0 = tid << 2;
    float a0 = 0.f, a1 = 0.f, a2 = 0.f, a3 = 0.f;
    const unsigned char* eb = ehb8 + ((size_t)(b * Sdim + s0) << 10) + d0;
    for (int sl = 0; sl < 50; sl++) {
        float pp = pL[sl];
        unsigned int u = *(const unsigned int*)(eb + ((size_t)sl << 10));
        float v[4];
        dec4(u, v);
        a0 = fmaf(pp, v[0], a0);
        a1 = fmaf(pp, v[1], a1);
        a2 = fmaf(pp, v[2], a2);
        a3 = fmaf(pp, v[3], a3);
    }
    *(float4*)&ctxp[(((size_t)(b * 8 + sc)) << 10) + d0] = make_float4(a0, a1, a2, a3);
}

// ---------------- per-step kernel B: K-split GRU GEMMs (R4 k_mm) ----------
// 144 blocks x 512 thr: 0..95 gi-ctx (4 K-chunks x 24 N), 96..143 gh (2 x 24).
// Combine weights: online-softmax e^{m_c-M}/tot (R7-verified).
__global__ __launch_bounds__(512) void k_mm5(
    const float* __restrict__ ctxp, const float* __restrict__ mcb,
    const float* __restrict__ sumc, const unsigned short* __restrict__ hb16,
    const unsigned short* __restrict__ Wihb, const unsigned short* __restrict__ Whhb,
    float* __restrict__ pgi, float* __restrict__ pgh,
    unsigned short* __restrict__ csb, int t)
{
    __shared__ __attribute__((aligned(16))) unsigned short As[64][264];
    __shared__ __attribute__((aligned(16))) unsigned short Ws[64][72];
    int bid = blockIdx.x, tid = threadIdx.x;
    int wave = tid >> 6, lane = tid & 63;
    bool isGi = bid < 96;
    int kc, nb;
    if (isGi) { kc = bid / 24; nb = bid - kc * 24; }
    else      { int x = bid - 96; kc = x / 24; nb = x - kc * 24; }
    int n0 = nb << 6;

    int r = tid >> 3, c0 = (tid & 7) << 5;
    if (isGi) {
        // online-softmax combine weights for batch r
        const float* mc = mcb + r * 8;
        const float* lc = sumc + r * 8;
        float M = mc[0];
        #pragma unroll
        for (int cc = 1; cc < 8; cc++) M = fmaxf(M, mc[cc]);
        float w8c[8], tot = 0.0f;
        #pragma unroll
        for (int cc = 0; cc < 8; cc++) { w8c[cc] = __expf(mc[cc] - M); tot += w8c[cc] * lc[cc]; }
        float inv = 1.0f / tot;
        const float* pc = ctxp + ((size_t)r << 13) + (kc << 8) + c0;
        #pragma unroll
        for (int k4 = 0; k4 < 8; k4++) {
            float ax = 0.f, ay = 0.f, az = 0.f, aw = 0.f;
            #pragma unroll
            for (int cc = 0; cc < 8; cc++) {
                float wgt = w8c[cc] * inv;
                float4 v = *(const float4*)(pc + (cc << 10) + (k4 << 2));
                ax = fmaf(wgt, v.x, ax); ay = fmaf(wgt, v.y, ay);
                az = fmaf(wgt, v.z, az); aw = fmaf(wgt, v.w, aw);
            }
            ushort4 u;
            u.x = f2bf(ax); u.y = f2bf(ay); u.z = f2bf(az); u.w = f2bf(aw);
            *(ushort4*)&As[r][c0 + (k4 << 2)] = u;
            if (nb == 0)
                *(ushort4*)&csb[(((size_t)(r * Tdim + t)) << 10) + (kc << 8) + c0 + (k4 << 2)] = u;
        }
    } else {
        const unsigned short* ph = hb16 + (size_t)r * 512 + (kc << 8) + c0;
        *(u16x8*)&As[r][c0]      = *(const u16x8*)ph;
        *(u16x8*)&As[r][c0 + 8]  = *(const u16x8*)(ph + 8);
        *(u16x8*)&As[r][c0 + 16] = *(const u16x8*)(ph + 16);
        *(u16x8*)&As[r][c0 + 24] = *(const u16x8*)(ph + 24);
    }
    __syncthreads();

    const unsigned short* Wsrc = isGi ? (Wihb + (size_t)n0 * H3 + 512 + (kc << 8))
                                      : (Whhb + (size_t)n0 * Hdim + (kc << 8));
    int ldw = isGi ? H3 : Hdim;
    int fr = lane & 15, fq = lane >> 4;
    int fi = wave >> 1, fj0 = (wave & 1) << 1;
    f32x4 acc0 = {0.f,0.f,0.f,0.f}, acc1 = {0.f,0.f,0.f,0.f};
    int rw = tid >> 3, cw2 = (tid & 7) << 3;
    for (int ch = 0; ch < 4; ch++) {
        __syncthreads();
        u16x8 wv8 = *(const u16x8*)(Wsrc + (size_t)rw * ldw + (ch << 6) + cw2);
        *(u16x8*)&Ws[rw][cw2] = wv8;
        __syncthreads();
        #pragma unroll
        for (int s = 0; s < 2; s++) {
            bf16x8 af = *(const bf16x8*)&As[(fi << 4) + fr][(ch << 6) + (s << 5) + (fq << 3)];
            bf16x8 b0 = *(const bf16x8*)&Ws[(fj0 << 4) + fr][(s << 5) + (fq << 3)];
            bf16x8 b1 = *(const bf16x8*)&Ws[((fj0 + 1) << 4) + fr][(s << 5) + (fq << 3)];
            acc0 = __builtin_amdgcn_mfma_f32_16x16x32_bf16(af, b0, acc0, 0, 0, 0);
            acc1 = __builtin_amdgcn_mfma_f32_16x16x32_bf16(af, b1, acc1, 0, 0, 0);
        }
    }
    float* outp = (isGi ? pgi : pgh) + (size_t)kc * Bdim * H3;
    int rowb = (fi << 4) + (fq << 2);
    #pragma unroll
    for (int r4 = 0; r4 < 4; r4++) {
        outp[(size_t)(rowb + r4) * H3 + n0 + (fj0 << 4) + fr] = acc0[r4];
        outp[(size_t)(rowb + r4) * H3 + n0 + ((fj0 + 1) << 4) + fr] = acc1[r4];
    }
}

// ---------------- final gates (t = Tdim) ----------------
__global__ __launch_bounds__(256) void k_gfin(
    const float* __restrict__ pgi, const float* __restrict__ pgh,
    const unsigned short* __restrict__ giEb,
    const float* __restrict__ bih, const float* __restrict__ bhh,
    const float* __restrict__ hb_old,
    float* __restrict__ ds, unsigned short* __restrict__ dsb,
    float* __restrict__ hlast)
{
    int b = blockIdx.x, tid = threadIdx.x;
    for (int jj = tid; jj < 512; jj += 256) {
        float gi0 = 0, gi1 = 0, gi2 = 0, gh0 = 0, gh1 = 0, gh2 = 0;
        #pragma unroll
        for (int cc = 0; cc < 4; cc++) {
            const float* p = pgi + ((size_t)(cc * 64 + b)) * H3;
            gi0 += p[jj]; gi1 += p[jj + 512]; gi2 += p[jj + 1024];
        }
        #pragma unroll
        for (int cc = 0; cc < 2; cc++) {
            const float* p = pgh + ((size_t)(cc * 64 + b)) * H3;
            gh0 += p[jj]; gh1 += p[jj + 512]; gh2 += p[jj + 1024];
        }
        size_t m = (size_t)b * Tdim + (Tdim - 1);
        const unsigned short* ge = giEb + m * H3;
        gi0 += bf2f(ge[jj])        + bih[jj];
        gi1 += bf2f(ge[jj + 512])  + bih[jj + 512];
        gi2 += bf2f(ge[jj + 1024]) + bih[jj + 1024];
        gh0 += bhh[jj]; gh1 += bhh[jj + 512]; gh2 += bhh[jj + 1024];
        float rg = sigm(gi0 + gh0);
        float zz = sigm(gi1 + gh1);
        float nn = fast_tanh(gi2 + rg * gh2);
        float hold = hb_old[(size_t)b * 512 + jj];
        float hn = (1.0f - zz) * nn + zz * hold;
        ds[m * 512 + jj] = hn;
        dsb[m * 512 + jj] = f2bf(hn);
        hlast[(size_t)b * 512 + jj] = hn;
    }
}

extern "C" void kernel_launch(void* const* d_in, const int* in_sizes, int n_in,
                              void* d_out, int out_size, void* d_ws, size_t ws_size,
                              hipStream_t stream) {
    const float* te  = (const float*)d_in[0];
    const float* eh  = (const float*)d_in[1];
    const float* ef  = (const float*)d_in[2];
    const float* Wi  = (const float*)d_in[3];
    const float* bi  = (const float*)d_in[4];
    const float* Wk  = (const float*)d_in[5];
    const float* Wq  = (const float*)d_in[6];
    const float* We  = (const float*)d_in[7];
    const float* Wih = (const float*)d_in[8];
    const float* Whh = (const float*)d_in[9];
    const float* bih = (const float*)d_in[10];
    const float* bhh = (const float*)d_in[11];
    const float* Wp  = (const float*)d_in[12];
    const float* bp  = (const float*)d_in[13];

    float* out     = (float*)d_out;
    float* out_ds  = out;
    float* out_hl  = out + (size_t)Bdim * Tdim * Hdim;
    float* out_pre = out_hl + (size_t)Bdim * Hdim;

    // ---- workspace ----
    char* w = (char*)d_ws;
    size_t o = 0;
    unsigned char*  pkb8 = (unsigned char*)(w + o);  o += (size_t)25600 * 512;
    unsigned char*  ehb8 = (unsigned char*)(w + o);  o += (size_t)25600 * 1024;
    unsigned short* teb  = (unsigned short*)(w + o); o += (size_t)6400 * 512 * 2;
    unsigned short* Wkb  = (unsigned short*)(w + o); o += (size_t)512 * 1024 * 2;
    unsigned short* Wihb = (unsigned short*)(w + o); o += (size_t)1536 * 1536 * 2;
    unsigned short* Whhb = (unsigned short*)(w + o); o += (size_t)1536 * 512 * 2;
    unsigned short* Wpb  = (unsigned short*)(w + o); o += (size_t)512 * 2048 * 2;
    unsigned char*  Wq8p = (unsigned char*)(w + o);  o += (size_t)512 * 512;
    unsigned short* dsb  = (unsigned short*)(w + o); o += (size_t)6400 * 512 * 2;
    unsigned short* csb  = (unsigned short*)(w + o); o += (size_t)6400 * 1024 * 2;
    unsigned short* giEb = (unsigned short*)(w + o); o += (size_t)6400 * 1536 * 2;
    unsigned short* hb16 = (unsigned short*)(w + o); o += (size_t)Bdim * 512 * 2;
    float* qbuf = (float*)(w + o); o += (size_t)Bdim * 512 * 4;
    float* hbuf = (float*)(w + o); o += (size_t)2 * Bdim * 512 * 4;   // S_t ping-pong
    float* ctxp = (float*)(w + o); o += (size_t)Bdim * 8 * 1024 * 4;
    float* mcb  = (float*)(w + o); o += 512 * 4;
    float* sumc = (float*)(w + o); o += 512 * 4;
    float* pgi  = (float*)(w + o); o += (size_t)4 * Bdim * H3 * 4;
    float* pgh  = (float*)(w + o); o += (size_t)2 * Bdim * H3 * 4;

    // ---- one-time prep (8 dispatches) ----
    k_cvt8<<<2048, 256, 0, stream>>>((const float4*)eh, (uchar4*)ehb8, 6553600);
    k_cvt<<<512, 256, 0, stream>>>((const float4*)te, (ushort4*)teb, 819200);
    k_cvtW<<<1024, 256, 0, stream>>>(
        (const float4*)Wk, (const float4*)Wih, (const float4*)Whh, (const float4*)Wp,
        (ushort4*)Wkb, (ushort4*)Wihb, (ushort4*)Whhb, (ushort4*)Wpb);
    k_packWq<<<256, 256, 0, stream>>>(Wq, (uchar4*)Wq8p);
    k_init<<<Bdim, 256, 0, stream>>>(ef, Wi, bi, hbuf, hb16);
    k_q0<<<Bdim, 512, 0, stream>>>(hbuf, Wq, qbuf);
    // proj_key = eh(f32) @ Wkb^T -> pkb8 (fp8), M=25600 N=512 K=1024
    k_mfma_gemm<<<dim3(200, 4), 256, 0, stream>>>(
        eh, nullptr, nullptr, nullptr, 1024, 0, 0, 1024, 1024,
        Wkb, 1024, nullptr, nullptr, pkb8, 512, nullptr, 1024);
    // gi_embed = teb @ Wihb[:, :512]^T -> giEb (bf16), M=6400 N=1536 K=512
    k_mfma_gemm<<<dim3(50, 12), 256, 0, stream>>>(
        nullptr, teb, teb, teb, 512, 512, 512, 512, 512,
        Wihb, 1536, nullptr, giEb, nullptr, 1536, nullptr, 512);

    // ---- scan: 2 wide dispatches per step ----
    for (int t = 0; t < Tdim; t++) {
        float* hb_old = hbuf + (size_t)((t > 0 ? (t - 1) : 0) & 1) * 32768;
        float* hb_new = hbuf + (size_t)(t & 1) * 32768;
        k_attn4<<<512, 256, 0, stream>>>(
            pkb8, ehb8, qbuf, pgi, pgh, giEb, bih, bhh,
            hb_old, hb_new, hb16, Wq8p, We,
            ctxp, mcb, sumc, out_ds, dsb, t);
        k_mm5<<<144, 512, 0, stream>>>(ctxp, mcb, sumc, hb16,
                                       Wihb, Whhb, pgi, pgh, csb, t);
    }
    // final gates -> S_100 -> ds[:,99], hlast
    k_gfin<<<Bdim, 256, 0, stream>>>(pgi, pgh, giEb, bih, bhh,
                                     hbuf + (size_t)((Tdim - 1) & 1) * 32768,
                                     out_ds, dsb, out_hl);

    // ---- final: pre = [teb | dsb | csb] @ Wpb^T + bp, M=6400 N=512 K=2048 ----
    k_mfma_gemm<<<dim3(50, 4), 256, 0, stream>>>(
        nullptr, teb, dsb, csb, 512, 512, 1024, 512, 1024,
        Wpb, 2048, out_pre, nullptr, nullptr, 512, bp, 2048);
}

// Round 10
// 4628.075 us; speedup vs baseline: 2.2163x; 1.5253x over previous
//
#include <hip/hip_runtime.h>
#include <cstddef>

// Decoder: B=64, S=400, T=100, E=512, H=512
// R10 = R4 (proven 3 wide kernels/step) minus ~51MB/step of L2/L3 traffic:
//  (1) atomic f32 ctx accumulation (complete ctx; kills k_mm's 49MB combine
//      amplification; no-max exp proven in R4), ping-pong zeroing via k_attn.
//  (2) fp8-packed Wq GEMV in k_gates (R9-proven): 16->8 MB/step.

#define Bdim 64
#define Sdim 400
#define Tdim 100
#define Edim 512
#define Hdim 512
#define H2   1024
#define H3   1536

typedef __attribute__((ext_vector_type(8))) short          bf16x8;
typedef __attribute__((ext_vector_type(8))) unsigned short u16x8;
typedef __attribute__((ext_vector_type(4))) float          f32x4;

__device__ __forceinline__ float bf2f(unsigned short u) {
    return __uint_as_float(((unsigned int)u) << 16);
}
__device__ __forceinline__ unsigned short f2bf(float f) {
    unsigned int x = __float_as_uint(f);
    x += 0x7fffu + ((x >> 16) & 1u);
    return (unsigned short)(x >> 16);
}
__device__ __forceinline__ float fast_tanh(float x) {
    float e = __expf(2.0f * x);
    return 1.0f - 2.0f / (e + 1.0f);
}
__device__ __forceinline__ float sigm(float x) {
    return 1.0f / (1.0f + __expf(-x));
}

// ---- OCP e4m3fn encode ----
__device__ __forceinline__ unsigned char f2fp8(float f) {
    unsigned u = __float_as_uint(f);
    unsigned s = (u >> 24) & 0x80u;
    float a = fabsf(f);
    if (a >= 448.0f) return (unsigned char)(s | 0x7Eu);
    if (a < 0.0009765625f) return (unsigned char)s;
    int e = (int)((u >> 23) & 0xFF) - 127;
    if (e < -6) {
        int q = (int)lrintf(a * 512.0f);
        return (unsigned char)(s | (unsigned)q);
    }
    unsigned mant = u & 0x7FFFFFu;
    unsigned keep = mant >> 20;
    unsigned rem  = mant & 0xFFFFFu;
    if (rem > 0x80000u || (rem == 0x80000u && (keep & 1u))) keep++;
    if (keep == 8u) { keep = 0u; e++; if (e > 8) return (unsigned char)(s | 0x7Eu); }
    return (unsigned char)(s | ((unsigned)(e + 7) << 3) | keep);
}

#if defined(__has_builtin)
#if __has_builtin(__builtin_amdgcn_cvt_pk_f32_fp8)
#define HWFP8 1
#endif
#endif
__device__ __forceinline__ float fp8sw(unsigned char v) {
    unsigned e = (v >> 3) & 15u, m = v & 7u, s = v >> 7;
    float f = e ? __uint_as_float(((e + 120u) << 23) | (m << 20))
                : (float)m * 0.001953125f;
    return s ? -f : f;
}
__device__ __forceinline__ void dec4(unsigned int w, float* o) {
#ifdef HWFP8
    auto lo = __builtin_amdgcn_cvt_pk_f32_fp8(w, false);
    auto hi = __builtin_amdgcn_cvt_pk_f32_fp8(w, true);
    o[0] = lo[0]; o[1] = lo[1]; o[2] = hi[0]; o[3] = hi[1];
#else
    o[0] = fp8sw(w & 0xFF); o[1] = fp8sw((w >> 8) & 0xFF);
    o[2] = fp8sw((w >> 16) & 0xFF); o[3] = fp8sw(w >> 24);
#endif
}

// ---------------- one-time kernels ----------------

__global__ void k_cvt(const float4* __restrict__ in, ushort4* __restrict__ out, int n4) {
    int i = blockIdx.x * blockDim.x + threadIdx.x;
    int stride = gridDim.x * blockDim.x;
    for (; i < n4; i += stride) {
        float4 v = in[i];
        ushort4 u;
        u.x = f2bf(v.x); u.y = f2bf(v.y); u.z = f2bf(v.z); u.w = f2bf(v.w);
        out[i] = u;
    }
}

__global__ void k_cvt8(const float4* __restrict__ in, uchar4* __restrict__ out, int n4) {
    int i = blockIdx.x * blockDim.x + threadIdx.x;
    int stride = gridDim.x * blockDim.x;
    for (; i < n4; i += stride) {
        float4 v = in[i];
        uchar4 u;
        u.x = f2fp8(v.x); u.y = f2fp8(v.y); u.z = f2fp8(v.z); u.w = f2fp8(v.w);
        out[i] = u;
    }
}

__global__ void k_cvtW(
    const float4* __restrict__ Wk, const float4* __restrict__ Wih,
    const float4* __restrict__ Whh, const float4* __restrict__ Wp,
    ushort4* __restrict__ oWk, ushort4* __restrict__ oWih,
    ushort4* __restrict__ oWhh, ushort4* __restrict__ oWp)
{
    int i = blockIdx.x * blockDim.x + threadIdx.x;
    int stride = gridDim.x * blockDim.x;
    for (; i < 1179648; i += stride) {
        const float4* src; ushort4* dst; int k = i;
        if (k < 131072)                     { src = Wk;  dst = oWk;  }
        else if ((k -= 131072) < 589824)    { src = Wih; dst = oWih; }
        else if ((k -= 589824) < 196608)    { src = Whh; dst = oWhh; }
        else { k -= 196608;                   src = Wp;  dst = oWp;  }
        float4 v = src[k];
        ushort4 u;
        u.x = f2bf(v.x); u.y = f2bf(v.y); u.z = f2bf(v.z); u.w = f2bf(v.w);
        dst[k] = u;
    }
}

// pack Wq into k4-major fp8: Wq8p[(k4*512 + j)] = fp8x4(Wq[j][4*k4..])
__global__ __launch_bounds__(256) void k_packWq(
    const float* __restrict__ Wq, uchar4* __restrict__ Wq8p)
{
    int i = blockIdx.x * 256 + threadIdx.x;     // 65536 uchar4 elements
    if (i >= 65536) return;
    int k4 = i >> 9, j = i & 511;
    const float* src = Wq + (size_t)j * 512 + (k4 << 2);
    uchar4 u;
    u.x = f2fp8(src[0]); u.y = f2fp8(src[1]);
    u.z = f2fp8(src[2]); u.w = f2fp8(src[3]);
    Wq8p[i] = u;
}

__global__ void k_zero(float* __restrict__ p, int n) {
    int i = blockIdx.x * blockDim.x + threadIdx.x;
    if (i < n) p[i] = 0.0f;
}

__global__ __launch_bounds__(256) void k_init(
    const float* __restrict__ ef, const float* __restrict__ Wi,
    const float* __restrict__ bi, float* __restrict__ h0,
    unsigned short* __restrict__ hb16)
{
    __shared__ float efs[1024];
    int b = blockIdx.x, tid = threadIdx.x;
    for (int i = tid; i < 1024; i += 256) efs[i] = ef[(size_t)b * 1024 + i];
    __syncthreads();
    for (int j = tid; j < 512; j += 256) {
        const float4* w4 = (const float4*)(Wi + (size_t)j * 1024);
        float acc = 0.0f;
        for (int k4 = 0; k4 < 256; k4++) {
            float4 wv = w4[k4];
            int k = k4 << 2;
            acc = fmaf(efs[k],   wv.x, acc);
            acc = fmaf(efs[k+1], wv.y, acc);
            acc = fmaf(efs[k+2], wv.z, acc);
            acc = fmaf(efs[k+3], wv.w, acc);
        }
        float h = fast_tanh(acc + bi[j]);
        h0[(size_t)b * 512 + j] = h;
        hb16[(size_t)b * 512 + j] = f2bf(h);
    }
}

__global__ __launch_bounds__(512) void k_q0(
    const float* __restrict__ h, const float* __restrict__ Wq,
    float* __restrict__ qbuf)
{
    __shared__ float hs[512];
    int b = blockIdx.x, j = threadIdx.x;
    hs[j] = h[(size_t)b * 512 + j];
    __syncthreads();
    const float4* w4 = (const float4*)(Wq + (size_t)j * 512);
    float acc = 0.0f;
    #pragma unroll 4
    for (int k4 = 0; k4 < 128; k4++) {
        float4 wv = w4[k4];
        int k = k4 << 2;
        acc = fmaf(hs[k],   wv.x, acc);
        acc = fmaf(hs[k+1], wv.y, acc);
        acc = fmaf(hs[k+2], wv.z, acc);
        acc = fmaf(hs[k+3], wv.w, acc);
    }
    qbuf[(size_t)b * 512 + j] = acc;
}

// MFMA bf16 GEMM: C[M][N] = A[M][K] @ B[N][K]^T. (verified R2/R4/R7-R9)
__global__ __launch_bounds__(256) void k_mfma_gemm(
    const float* __restrict__ Af,
    const unsigned short* __restrict__ A0, const unsigned short* __restrict__ A1,
    const unsigned short* __restrict__ A2,
    int ld0, int ld1, int ld2, int s1, int s2,
    const unsigned short* __restrict__ Bw, int ldb,
    float* __restrict__ Cf, unsigned short* __restrict__ Cb,
    unsigned char* __restrict__ C8, int ldc,
    const float* __restrict__ bias, int K)
{
    __shared__ __attribute__((aligned(16))) unsigned short As[128][40];
    __shared__ __attribute__((aligned(16))) unsigned short Bs[128][40];
    int m0 = blockIdx.x << 7, n0 = blockIdx.y << 7;
    int tid = threadIdx.x;
    int wave = tid >> 6, lane = tid & 63;
    int wr = (wave >> 1) << 6, wc = (wave & 1) << 6;
    int fr = lane & 15, fq = lane >> 4;
    f32x4 acc[4][4];
    #pragma unroll
    for (int i = 0; i < 4; i++)
        #pragma unroll
        for (int j = 0; j < 4; j++)
            acc[i][j] = (f32x4){0.f, 0.f, 0.f, 0.f};
    int lrow = tid >> 1;
    int lk = (tid & 1) << 4;
    for (int k0 = 0; k0 < K; k0 += 32) {
        u16x8 av0, av1;
        if (Af) {
            const float* ap = Af + (size_t)(m0 + lrow) * ld0 + k0 + lk;
            float4 f0 = *(const float4*)ap;
            float4 f1 = *(const float4*)(ap + 4);
            float4 f2 = *(const float4*)(ap + 8);
            float4 f3 = *(const float4*)(ap + 12);
            av0[0]=f2bf(f0.x); av0[1]=f2bf(f0.y); av0[2]=f2bf(f0.z); av0[3]=f2bf(f0.w);
            av0[4]=f2bf(f1.x); av0[5]=f2bf(f1.y); av0[6]=f2bf(f1.z); av0[7]=f2bf(f1.w);
            av1[0]=f2bf(f2.x); av1[1]=f2bf(f2.y); av1[2]=f2bf(f2.z); av1[3]=f2bf(f2.w);
            av1[4]=f2bf(f3.x); av1[5]=f2bf(f3.y); av1[6]=f2bf(f3.z); av1[7]=f2bf(f3.w);
        } else {
            const unsigned short* Ap; int lda_, ka;
            if (k0 < s1)      { Ap = A0; lda_ = ld0; ka = k0; }
            else if (k0 < s2) { Ap = A1; lda_ = ld1; ka = k0 - s1; }
            else              { Ap = A2; lda_ = ld2; ka = k0 - s2; }
            const unsigned short* ap = Ap + (size_t)(m0 + lrow) * lda_ + ka + lk;
            av0 = *(const u16x8*)ap;
            av1 = *(const u16x8*)(ap + 8);
        }
        const unsigned short* bp_ = Bw + (size_t)(n0 + lrow) * ldb + k0 + lk;
        u16x8 bv0 = *(const u16x8*)bp_;
        u16x8 bv1 = *(const u16x8*)(bp_ + 8);
        __syncthreads();
        *(u16x8*)&As[lrow][lk] = av0;
        *(u16x8*)&As[lrow][lk + 8] = av1;
        *(u16x8*)&Bs[lrow][lk] = bv0;
        *(u16x8*)&Bs[lrow][lk + 8] = bv1;
        __syncthreads();
        bf16x8 af[4], bf[4];
        #pragma unroll
        for (int i = 0; i < 4; i++) {
            af[i] = *(const bf16x8*)&As[wr + (i << 4) + fr][fq << 3];
            bf[i] = *(const bf16x8*)&Bs[wc + (i << 4) + fr][fq << 3];
        }
        #pragma unroll
        for (int i = 0; i < 4; i++)
            #pragma unroll
            for (int j = 0; j < 4; j++)
                acc[i][j] = __builtin_amdgcn_mfma_f32_16x16x32_bf16(af[i], bf[j], acc[i][j], 0, 0, 0);
    }
    #pragma unroll
    for (int j = 0; j < 4; j++) {
        int col = n0 + wc + (j << 4) + fr;
        float bv = bias ? bias[col] : 0.0f;
        #pragma unroll
        for (int i = 0; i < 4; i++) {
            int rbase = m0 + wr + (i << 4) + (fq << 2);
            #pragma unroll
            for (int r = 0; r < 4; r++) {
                float v = acc[i][j][r] + bv;
                if (C8)      C8[(size_t)(rbase + r) * ldc + col] = f2fp8(v);
                else if (Cb) Cb[(size_t)(rbase + r) * ldc + col] = f2bf(v);
                else         Cf[(size_t)(rbase + r) * ldc + col] = v;
            }
        }
    }
}

// ---------------- per-step kernel 1: attention ----------------
// 512 blocks (b = bid>>3, c = bid&7; 8 s-chunks of 50), 256 threads.
// No-max softmax (R4-proven). exp-weighted context accumulated ATOMICALLY
// into complete ctxf[t&1]; sum of exp into sumcA[t&1]. Slot (t&1)^1 is
// zeroed here for step t+1 (kernel-boundary ordering makes this safe).
__global__ __launch_bounds__(256) void k_attn(
    const unsigned char* __restrict__ pkb8, const unsigned char* __restrict__ ehb8,
    const float* __restrict__ qbuf, const float* __restrict__ We,
    float* __restrict__ ctxf, float* __restrict__ sumcA, int t)
{
    int bid = blockIdx.x;
    int b = bid >> 3, c = bid & 7;
    int s0 = c * 50;
    int tid = threadIdx.x, wave = tid >> 6, lane = tid & 63;
    int s = t & 1;
    __shared__ float eL[52], pL[52];

    // zero the other ping-pong slot for next step
    {
        int gid = bid * 256 + tid;
        float* octx = ctxf + ((size_t)(1 - s) << 16);
        if (gid < 65536) octx[gid] = 0.0f;
        if (gid < 64) sumcA[(1 - s) * 64 + gid] = 0.0f;
    }

    float q8[8], w8[8];
    {
        const float4* qp = (const float4*)(qbuf + (size_t)b * 512 + (lane << 3));
        float4 q0 = qp[0], q1 = qp[1];
        q8[0]=q0.x; q8[1]=q0.y; q8[2]=q0.z; q8[3]=q0.w;
        q8[4]=q1.x; q8[5]=q1.y; q8[6]=q1.z; q8[7]=q1.w;
        const float4* wp = (const float4*)(We + (lane << 3));
        float4 w0 = wp[0], w1 = wp[1];
        w8[0]=w0.x; w8[1]=w0.y; w8[2]=w0.z; w8[3]=w0.w;
        w8[4]=w1.x; w8[5]=w1.y; w8[6]=w1.z; w8[7]=w1.w;
    }
    // phase A: energies, one wave per s row
    for (int sl = wave; sl < 50; sl += 4) {
        const unsigned char* pr = pkb8 + ((size_t)(b * Sdim + s0 + sl) << 9) + (lane << 3);
        uint2 u = *(const uint2*)pr;
        float p[8];
        dec4(u.x, p); dec4(u.y, p + 4);
        float sum = 0.0f;
        #pragma unroll
        for (int jj = 0; jj < 8; jj++)
            sum = fmaf(fast_tanh(q8[jj] + p[jj]), w8[jj], sum);
        #pragma unroll
        for (int off = 32; off > 0; off >>= 1) sum += __shfl_xor(sum, off, 64);
        if (lane == 0) eL[sl] = sum;
    }
    __syncthreads();
    // phase B: p = exp(e) (energies bounded; no max — R4-proven), chunk sum
    if (wave == 0) {
        float pv = 0.0f;
        if (lane < 50) { pv = __expf(eL[lane]); pL[lane] = pv; }
        float ssum = pv;
        #pragma unroll
        for (int off = 32; off > 0; off >>= 1) ssum += __shfl_xor(ssum, off, 64);
        if (lane == 0) atomicAdd(&sumcA[s * 64 + b], ssum);
    }
    __syncthreads();
    // phase C: exp-weighted context, atomically accumulated (complete ctx)
    int d0 = tid << 2;
    float a0 = 0.f, a1 = 0.f, a2 = 0.f, a3 = 0.f;
    const unsigned char* eb = ehb8 + ((size_t)(b * Sdim + s0) << 10) + d0;
    for (int sl = 0; sl < 50; sl++) {
        float pp = pL[sl];
        unsigned int u = *(const unsigned int*)(eb + ((size_t)sl << 10));
        float v[4];
        dec4(u, v);
        a0 = fmaf(pp, v[0], a0);
        a1 = fmaf(pp, v[1], a1);
        a2 = fmaf(pp, v[2], a2);
        a3 = fmaf(pp, v[3], a3);
    }
    float* cp = ctxf + ((size_t)s << 16) + ((size_t)b << 10) + d0;
    atomicAdd(cp + 0, a0);
    atomicAdd(cp + 1, a1);
    atomicAdd(cp + 2, a2);
    atomicAdd(cp + 3, a3);
}

// ---------------- per-step kernel 2: K-split GRU GEMMs ----------
// 144 blocks x 512 thr: 0..95 gi-ctx (4 K-chunks x 24 N), 96..143 gh (2 x 24).
// Reads COMPLETE ctxf (atomic-combined) — no per-block combine.
__global__ __launch_bounds__(512) void k_mm(
    const float* __restrict__ ctxf, const float* __restrict__ sumcA,
    const unsigned short* __restrict__ hb16,
    const unsigned short* __restrict__ Wihb, const unsigned short* __restrict__ Whhb,
    float* __restrict__ pgi, float* __restrict__ pgh,
    unsigned short* __restrict__ csb, int t)
{
    __shared__ __attribute__((aligned(16))) unsigned short As[64][264];
    __shared__ __attribute__((aligned(16))) unsigned short Ws[64][72];
    int bid = blockIdx.x, tid = threadIdx.x;
    int wave = tid >> 6, lane = tid & 63;
    int s = t & 1;
    bool isGi = bid < 96;
    int kc, nb;
    if (isGi) { kc = bid / 24; nb = bid - kc * 24; }
    else      { int x = bid - 96; kc = x / 24; nb = x - kc * 24; }
    int n0 = nb << 6;

    int r = tid >> 3, c0 = (tid & 7) << 5;
    if (isGi) {
        float inv = 1.0f / sumcA[s * 64 + r];
        const float* pc = ctxf + ((size_t)s << 16) + ((size_t)r << 10) + (kc << 8) + c0;
        #pragma unroll
        for (int k4 = 0; k4 < 8; k4++) {
            float4 v = *(const float4*)(pc + (k4 << 2));
            ushort4 u;
            u.x = f2bf(v.x * inv); u.y = f2bf(v.y * inv);
            u.z = f2bf(v.z * inv); u.w = f2bf(v.w * inv);
            *(ushort4*)&As[r][c0 + (k4 << 2)] = u;
            if (nb == 0)
                *(ushort4*)&csb[(((size_t)(r * Tdim + t)) << 10) + (kc << 8) + c0 + (k4 << 2)] = u;
        }
    } else {
        const unsigned short* ph = hb16 + (size_t)r * 512 + (kc << 8) + c0;
        *(u16x8*)&As[r][c0]      = *(const u16x8*)ph;
        *(u16x8*)&As[r][c0 + 8]  = *(const u16x8*)(ph + 8);
        *(u16x8*)&As[r][c0 + 16] = *(const u16x8*)(ph + 16);
        *(u16x8*)&As[r][c0 + 24] = *(const u16x8*)(ph + 24);
    }
    __syncthreads();

    const unsigned short* Wsrc = isGi ? (Wihb + (size_t)n0 * H3 + 512 + (kc << 8))
                                      : (Whhb + (size_t)n0 * Hdim + (kc << 8));
    int ldw = isGi ? H3 : Hdim;
    int fr = lane & 15, fq = lane >> 4;
    int fi = wave >> 1, fj0 = (wave & 1) << 1;
    f32x4 acc0 = {0.f,0.f,0.f,0.f}, acc1 = {0.f,0.f,0.f,0.f};
    int rw = tid >> 3, cw2 = (tid & 7) << 3;
    for (int ch = 0; ch < 4; ch++) {
        __syncthreads();
        u16x8 wv8 = *(const u16x8*)(Wsrc + (size_t)rw * ldw + (ch << 6) + cw2);
        *(u16x8*)&Ws[rw][cw2] = wv8;
        __syncthreads();
        #pragma unroll
        for (int ss = 0; ss < 2; ss++) {
            bf16x8 af = *(const bf16x8*)&As[(fi << 4) + fr][(ch << 6) + (ss << 5) + (fq << 3)];
            bf16x8 b0 = *(const bf16x8*)&Ws[(fj0 << 4) + fr][(ss << 5) + (fq << 3)];
            bf16x8 b1 = *(const bf16x8*)&Ws[((fj0 + 1) << 4) + fr][(ss << 5) + (fq << 3)];
            acc0 = __builtin_amdgcn_mfma_f32_16x16x32_bf16(af, b0, acc0, 0, 0, 0);
            acc1 = __builtin_amdgcn_mfma_f32_16x16x32_bf16(af, b1, acc1, 0, 0, 0);
        }
    }
    float* outp = (isGi ? pgi : pgh) + (size_t)kc * Bdim * H3;
    int rowb = (fi << 4) + (fq << 2);
    #pragma unroll
    for (int r4 = 0; r4 < 4; r4++) {
        outp[(size_t)(rowb + r4) * H3 + n0 + (fj0 << 4) + fr] = acc0[r4];
        outp[(size_t)(rowb + r4) * H3 + n0 + ((fj0 + 1) << 4) + fr] = acc1[r4];
    }
}

// ---------------- per-step kernel 3: gates + h + q (fp8 Wq) ----------------
__global__ __launch_bounds__(512) void k_gates(
    const float* __restrict__ pgi, const float* __restrict__ pgh,
    const unsigned short* __restrict__ giEb,
    const float* __restrict__ bih, const float* __restrict__ bhh,
    const float* __restrict__ hcur, float* __restrict__ hnext,
    const unsigned char* __restrict__ Wq8p, float* __restrict__ qbuf,
    float* __restrict__ ds, unsigned short* __restrict__ dsb,
    unsigned short* __restrict__ hb16, float* __restrict__ hlast, int t)
{
    int b = blockIdx.x, j = threadIdx.x;
    size_t m = (size_t)b * Tdim + t;
    float gir = 0, giz = 0, gin = 0;
    #pragma unroll
    for (int cc = 0; cc < 4; cc++) {
        const float* p = pgi + ((size_t)cc * Bdim + b) * H3;
        gir += p[j]; giz += p[j + 512]; gin += p[j + 1024];
    }
    const unsigned short* ge = giEb + m * H3;
    gir += bf2f(ge[j]); giz += bf2f(ge[j + 512]); gin += bf2f(ge[j + 1024]);
    float ghr = 0, ghz = 0, ghn = 0;
    #pragma unroll
    for (int cc = 0; cc < 2; cc++) {
        const float* p = pgh + ((size_t)cc * Bdim + b) * H3;
        ghr += p[j]; ghz += p[j + 512]; ghn += p[j + 1024];
    }
    gir += bih[j];        ghr += bhh[j];
    giz += bih[j + 512];  ghz += bhh[j + 512];
    gin += bih[j + 1024]; ghn += bhh[j + 1024];
    float rg = sigm(gir + ghr);
    float z  = sigm(giz + ghz);
    float nn = fast_tanh(gin + rg * ghn);
    float hp = hcur[(size_t)b * 512 + j];
    float hn = (1.0f - z) * nn + z * hp;
    ds[m * 512 + j] = hn;
    dsb[m * 512 + j] = f2bf(hn);
    hb16[(size_t)b * 512 + j] = f2bf(hn);
    hnext[(size_t)b * 512 + j] = hn;
    hlast[(size_t)b * 512 + j] = hn;   // final overwrite = h_last
    // q_{t+1} = h_new @ Wq^T  (fp8 packed k4-major, coalesced; R9-proven)
    __shared__ float hs[512];
    hs[j] = hn;
    __syncthreads();
    float acc = 0.0f;
    const unsigned int* wp = (const unsigned int*)Wq8p + j;
    #pragma unroll 4
    for (int k4 = 0; k4 < 128; k4++) {
        float4 hv = *(const float4*)&hs[k4 << 2];
        unsigned int wv = wp[(size_t)k4 << 9];
        float d[4];
        dec4(wv, d);
        acc = fmaf(hv.x, d[0], acc);
        acc = fmaf(hv.y, d[1], acc);
        acc = fmaf(hv.z, d[2], acc);
        acc = fmaf(hv.w, d[3], acc);
    }
    qbuf[(size_t)b * 512 + j] = acc;
}

extern "C" void kernel_launch(void* const* d_in, const int* in_sizes, int n_in,
                              void* d_out, int out_size, void* d_ws, size_t ws_size,
                              hipStream_t stream) {
    const float* te  = (const float*)d_in[0];
    const float* eh  = (const float*)d_in[1];
    const float* ef  = (const float*)d_in[2];
    const float* Wi  = (const float*)d_in[3];
    const float* bi  = (const float*)d_in[4];
    const float* Wk  = (const float*)d_in[5];
    const float* Wq  = (const float*)d_in[6];
    const float* We  = (const float*)d_in[7];
    const float* Wih = (const float*)d_in[8];
    const float* Whh = (const float*)d_in[9];
    const float* bih = (const float*)d_in[10];
    const float* bhh = (const float*)d_in[11];
    const float* Wp  = (const float*)d_in[12];
    const float* bp  = (const float*)d_in[13];

    float* out     = (float*)d_out;
    float* out_ds  = out;
    float* out_hl  = out + (size_t)Bdim * Tdim * Hdim;
    float* out_pre = out_hl + (size_t)Bdim * Hdim;

    // ---- workspace ----
    char* w = (char*)d_ws;
    size_t o = 0;
    unsigned char*  pkb8 = (unsigned char*)(w + o);  o += (size_t)25600 * 512;
    unsigned char*  ehb8 = (unsigned char*)(w + o);  o += (size_t)25600 * 1024;
    unsigned short* teb  = (unsigned short*)(w + o); o += (size_t)6400 * 512 * 2;
    unsigned short* Wkb  = (unsigned short*)(w + o); o += (size_t)512 * 1024 * 2;
    unsigned short* Wihb = (unsigned short*)(w + o); o += (size_t)1536 * 1536 * 2;
    unsigned short* Whhb = (unsigned short*)(w + o); o += (size_t)1536 * 512 * 2;
    unsigned short* Wpb  = (unsigned short*)(w + o); o += (size_t)512 * 2048 * 2;
    unsigned char*  Wq8p = (unsigned char*)(w + o);  o += (size_t)512 * 512;
    unsigned short* dsb  = (unsigned short*)(w + o); o += (size_t)6400 * 512 * 2;
    unsigned short* csb  = (unsigned short*)(w + o); o += (size_t)6400 * 1024 * 2;
    unsigned short* giEb = (unsigned short*)(w + o); o += (size_t)6400 * 1536 * 2;
    unsigned short* hb16 = (unsigned short*)(w + o); o += (size_t)Bdim * 512 * 2;
    float* qbuf  = (float*)(w + o); o += (size_t)Bdim * 512 * 4;
    float* hbuf  = (float*)(w + o); o += (size_t)2 * Bdim * 512 * 4;   // ping-pong
    float* ctxf  = (float*)(w + o); o += (size_t)2 * Bdim * 1024 * 4;  // ping-pong
    float* sumcA = (float*)(w + o); o += 128 * 4;
    float* pgi   = (float*)(w + o); o += (size_t)4 * Bdim * H3 * 4;
    float* pgh   = (float*)(w + o); o += (size_t)2 * Bdim * H3 * 4;

    // ---- one-time prep ----
    k_cvt8<<<2048, 256, 0, stream>>>((const float4*)eh, (uchar4*)ehb8, 6553600);
    k_cvt<<<512, 256, 0, stream>>>((const float4*)te, (ushort4*)teb, 819200);
    k_cvtW<<<1024, 256, 0, stream>>>(
        (const float4*)Wk, (const float4*)Wih, (const float4*)Whh, (const float4*)Wp,
        (ushort4*)Wkb, (ushort4*)Wihb, (ushort4*)Whhb, (ushort4*)Wpb);
    k_packWq<<<256, 256, 0, stream>>>(Wq, (uchar4*)Wq8p);
    k_zero<<<514, 256, 0, stream>>>(ctxf, 2 * 65536 + 128);   // ctxf + sumcA contiguous
    k_init<<<Bdim, 256, 0, stream>>>(ef, Wi, bi, hbuf, hb16);
    k_q0<<<Bdim, 512, 0, stream>>>(hbuf, Wq, qbuf);
    // proj_key = eh(f32) @ Wkb^T -> pkb8 (fp8), M=25600 N=512 K=1024
    k_mfma_gemm<<<dim3(200, 4), 256, 0, stream>>>(
        eh, nullptr, nullptr, nullptr, 1024, 0, 0, 1024, 1024,
        Wkb, 1024, nullptr, nullptr, pkb8, 512, nullptr, 1024);
    // gi_embed = teb @ Wihb[:, :512]^T -> giEb (bf16), M=6400 N=1536 K=512
    k_mfma_gemm<<<dim3(50, 12), 256, 0, stream>>>(
        nullptr, teb, teb, teb, 512, 512, 512, 512, 512,
        Wihb, 1536, nullptr, giEb, nullptr, 1536, nullptr, 512);

    // ---- scan: 3 wide dispatches per step (R4 structure, less traffic) ----
    for (int t = 0; t < Tdim; t++) {
        float* hcur  = hbuf + (size_t)(t & 1) * 32768;
        float* hnext = hbuf + (size_t)((t + 1) & 1) * 32768;
        k_attn<<<512, 256, 0, stream>>>(pkb8, ehb8, qbuf, We, ctxf, sumcA, t);
        k_mm<<<144, 512, 0, stream>>>(ctxf, sumcA, hb16, Wihb, Whhb, pgi, pgh, csb, t);
        k_gates<<<Bdim, 512, 0, stream>>>(pgi, pgh, giEb, bih, bhh, hcur, hnext,
                                          Wq8p, qbuf, out_ds, dsb, hb16, out_hl, t);
    }

    // ---- final: pre = [teb | dsb | csb] @ Wpb^T + bp, M=6400 N=512 K=2048 ----
    k_mfma_gemm<<<dim3(50, 4), 256, 0, stream>>>(
        nullptr, teb, dsb, csb, 512, 512, 1024, 512, 1024,
        Wpb, 2048, out_pre, nullptr, nullptr, 512, bp, 2048);
}